// Round 12
// baseline (338.464 us; speedup 1.0000x reference)
//
#include <hip/hip_runtime.h>

typedef short s16x8 __attribute__((ext_vector_type(8)));     // 8x 16-bit in 4 VGPRs
typedef _Float16 h16x8 __attribute__((ext_vector_type(8)));  // 8 fp16 in 4 VGPRs
typedef float f32x4 __attribute__((ext_vector_type(4)));

__device__ __forceinline__ unsigned short f2bf(float f) {
    unsigned int u = __builtin_bit_cast(unsigned int, f);
    u += 0x7FFFu + ((u >> 16) & 1u);           // round-to-nearest-even
    return (unsigned short)(u >> 16);
}
__device__ __forceinline__ float bf2f(unsigned short h) {
    unsigned int u = ((unsigned int)h) << 16;
    return __builtin_bit_cast(float, u);
}
__device__ __forceinline__ unsigned short f2h(float f) {
    _Float16 h = (_Float16)f;                  // v_cvt_f16_f32, RNE
    return __builtin_bit_cast(unsigned short, h);
}
__device__ __forceinline__ float h2f(unsigned short u) {
    return (float)__builtin_bit_cast(_Float16, u);
}

// legacy swizzle for the [128][32] tiles (fallback kernels)
__device__ __forceinline__ int swz(int row, int kbyte) {
    return (row * 64 + kbyte) ^ (((row >> 1) & 3) << 4);
}

// async global->LDS, 16B per lane; LDS dest is wave-uniform base + lane*16.
__device__ __forceinline__ void gl16(const void* g, void* l) {
    __builtin_amdgcn_global_load_lds(
        (__attribute__((address_space(1))) void*)(g),
        (__attribute__((address_space(3))) void*)(l), 16, 0, 0);
}

// ============================================================================
// score_8ph: 256x256 tile, BK=64, 512 threads (8 waves: 2M x 4N).
// Register-carry, SINGLE vmcnt(8)/K-tile, ONE barrier per phase.
// Round-12: bf1's 4 ds_reads HOISTED to P1 (slot B1/bp last written at P4 of
// tile tau-2, drained by tau-1's vmcnt(8) -> legal at P1). P2's MFMA now has
// zero LDS dependency. Slot ring unchanged: P2 stages A0(tau+2), P3 B0,
// P4 B1+A1; vmcnt(8) at P4. Tails: nt-2 -> vmcnt(0); nt-1 -> none.
// OUTMODE: 0 = fp32 out (+bias), 1 = fp16 out (+bias).
// ============================================================================
#define STG(ptr, rowbase, tt, bufp, slot) do {                                      \
    gl16((ptr) + (long)((rowbase) + sl) * K + (tt) * 64 + koff,                     \
         &lds[bufp][slot][(unsigned)t * 8]);                                        \
    gl16((ptr) + (long)((rowbase) + 64 + sl) * K + (tt) * 64 + koff,                \
         &lds[bufp][slot][4096u + (unsigned)t * 8]);                                \
} while (0)

#define LDA(qi_) do {                                                               \
    const char* ba_ = (const char*)&lds[bp][qi_][0];                                \
    _Pragma("unroll")                                                               \
    for (int ks_ = 0; ks_ < 2; ++ks_)                                               \
        _Pragma("unroll")                                                           \
        for (int f_ = 0; f_ < 4; ++f_) {                                            \
            const int row_ = wm * 64 + f_ * 16 + lr;                                \
            af[ks_][f_] = *(const h16x8*)(ba_ + row_ * 128 +                        \
                            ((ks_ * 64 + kg16) ^ ((row_ & 7) << 4)));               \
        }                                                                           \
} while (0)

#define LDB(dst_, qj_) do {                                                         \
    const char* bb_ = (const char*)&lds[bp][2 + (qj_)][0];                          \
    _Pragma("unroll")                                                               \
    for (int ks_ = 0; ks_ < 2; ++ks_)                                               \
        _Pragma("unroll")                                                           \
        for (int g_ = 0; g_ < 2; ++g_) {                                            \
            const int row_ = wn * 32 + g_ * 16 + lr;                                \
            dst_[ks_][g_] = *(const h16x8*)(bb_ + row_ * 128 +                      \
                            ((ks_ * 64 + kg16) ^ ((row_ & 7) << 4)));               \
        }                                                                           \
} while (0)

#define BARR() do {                                                                 \
    __builtin_amdgcn_s_barrier();                                                   \
    __builtin_amdgcn_sched_barrier(0);                                              \
} while (0)

// MFMA cluster without trailing barrier
#define MMNB(qi_, qj_, bfv_) do {                                                   \
    __builtin_amdgcn_s_setprio(1);                                                  \
    _Pragma("unroll")                                                               \
    for (int ks_ = 0; ks_ < 2; ++ks_)                                               \
        _Pragma("unroll")                                                           \
        for (int f_ = 0; f_ < 4; ++f_)                                              \
            _Pragma("unroll")                                                       \
            for (int g_ = 0; g_ < 2; ++g_)                                          \
                acc[qi_][qj_][f_][g_] = __builtin_amdgcn_mfma_f32_16x16x32_f16(     \
                    af[ks_][f_], bfv_[ks_][g_], acc[qi_][qj_][f_][g_], 0, 0, 0);    \
    __builtin_amdgcn_s_setprio(0);                                                  \
} while (0)

template<int F16OUT>
__global__ __launch_bounds__(512, 2) void score_8ph(
    const unsigned short* __restrict__ A, const unsigned short* __restrict__ Bm,
    const float* __restrict__ bias, void* __restrict__ Cv,
    int M, int N, int K, int nbx)
{
    __shared__ unsigned short lds[2][4][8192];   // [buf][slot A0,A1,B0,B1] 128 KiB

    const int bid = blockIdx.x;
    const int cpx = gridDim.x >> 3;
    const int sw  = (bid & 7) * cpx + (bid >> 3);   // XCD-contiguous remap
    const int m0 = (sw / nbx) * 256, n0 = (sw % nbx) * 256;

    const int t = threadIdx.x;
    const int l = t & 63, w = t >> 6;
    const int wm = w >> 2, wn = w & 3;
    const int lr = l & 15;
    const int kg16 = (l >> 4) * 16;

    const int sl   = w * 8 + (l >> 3);           // 0..63
    const int koff = ((l & 7) ^ (sl & 7)) * 8;   // inverse-swizzle src k-offset (elems)

    h16x8 af[2][4], bf0[2][2], bf1[2][2];
    f32x4 acc[2][2][4][2];
    #pragma unroll
    for (int a = 0; a < 2; ++a)
        #pragma unroll
        for (int b = 0; b < 2; ++b)
            #pragma unroll
            for (int c = 0; c < 4; ++c)
                #pragma unroll
                for (int d = 0; d < 2; ++d)
                    acc[a][b][c][d] = (f32x4){0.f, 0.f, 0.f, 0.f};

    const int nt = K >> 6;   // requires nt >= 3

    // prologue: stage tiles 0 (buf0) and 1 (buf1) fully; drain tile 0.
    STG(A,  m0,       0, 0, 0);
    STG(Bm, n0,       0, 0, 2);
    STG(Bm, n0 + 128, 0, 0, 3);
    STG(A,  m0 + 128, 0, 0, 1);
    STG(A,  m0,       1, 1, 0);
    STG(Bm, n0,       1, 1, 2);
    STG(Bm, n0 + 128, 1, 1, 3);
    STG(A,  m0 + 128, 1, 1, 1);
    asm volatile("s_waitcnt vmcnt(8)" ::: "memory");
    BARR();

    int tau = 0;
    for (; tau < nt - 2; ++tau) {
        const int bp = tau & 1;
        // P1 (0,0): load af0, bf0, AND bf1 (hoisted)
        LDA(0); LDB(bf0, 0); LDB(bf1, 1);
        MMNB(0, 0, bf0);
        BARR();
        // P2 (0,1): no LDS reads
        STG(A, m0, tau + 2, bp, 0);
        MMNB(0, 1, bf1);
        BARR();
        // P3 (1,1)
        LDA(1);
        STG(Bm, n0, tau + 2, bp, 2);
        MMNB(1, 1, bf1);
        BARR();
        // P4 (1,0)
        STG(Bm, n0 + 128, tau + 2, bp, 3);
        STG(A,  m0 + 128, tau + 2, bp, 1);
        asm volatile("s_waitcnt vmcnt(8)" ::: "memory");
        MMNB(1, 0, bf0);
        BARR();
    }
    {   // tile nt-2: no staging; drain at P4
        const int bp = tau & 1;
        LDA(0); LDB(bf0, 0); LDB(bf1, 1);
        MMNB(0, 0, bf0);
        BARR();
        MMNB(0, 1, bf1);
        BARR();
        LDA(1);
        MMNB(1, 1, bf1);
        BARR();
        asm volatile("s_waitcnt vmcnt(0)" ::: "memory");
        MMNB(1, 0, bf0);
        BARR();
        ++tau;
    }
    {   // tile nt-1: no staging, nothing outstanding
        const int bp = tau & 1;
        LDA(0); LDB(bf0, 0); LDB(bf1, 1);
        MMNB(0, 0, bf0);
        BARR();
        MMNB(0, 1, bf1);
        BARR();
        LDA(1);
        MMNB(1, 1, bf1);
        BARR();
        MMNB(1, 0, bf0);
    }

    // epilogue
    #pragma unroll
    for (int qi = 0; qi < 2; ++qi)
        #pragma unroll
        for (int qj = 0; qj < 2; ++qj)
            #pragma unroll
            for (int f = 0; f < 4; ++f)
                #pragma unroll
                for (int g = 0; g < 2; ++g) {
                    const int row = m0 + qi * 128 + wm * 64 + f * 16 + (l >> 4) * 4;
                    const int col = n0 + qj * 128 + wn * 32 + g * 16 + lr;
                    const float badd = bias[col];
                    if (F16OUT) {
                        unsigned short* C = (unsigned short*)Cv;
                        #pragma unroll
                        for (int r = 0; r < 4; ++r)
                            C[(long)(row + r) * N + col] =
                                f2h(acc[qi][qj][f][g][r] + badd);
                    } else {
                        float* C = (float*)Cv;
                        #pragma unroll
                        for (int r = 0; r < 4; ++r)
                            C[(long)(row + r) * N + col] = acc[qi][qj][f][g][r] + badd;
                    }
                }
}

// ============================================================================
// pv_ring: 128x128 fp16 NT GEMM, 3-buffer depth-2 counted-vmcnt ring (round 12).
// Stage tile tau+2 into buf[(tau+2)%3] at tile start; read buf[tau%3];
// one barrier per tile with vmcnt(8) (drains tau+1's stages, keeps tau+2's
// in flight). LDS 96KB. A=[M,K], B=[N,K], batched over z.
// ============================================================================
__global__ __launch_bounds__(256, 1) void pv_ring(
    const unsigned short* __restrict__ A, const unsigned short* __restrict__ Bm,
    float* __restrict__ C, int M, int N, int K,
    long strideA, long strideB, long strideC)
{
    __shared__ unsigned short lds[3][2][128 * 64];   // 96 KiB

    const int bz = blockIdx.z;
    const unsigned short* Ab = A  + (long)bz * strideA;
    const unsigned short* Bb = Bm + (long)bz * strideB;
    float* Cb = C + (long)bz * strideC;
    const int m0 = blockIdx.x * 128, n0 = blockIdx.y * 128;

    const int t = threadIdx.x;
    const int l = t & 63, w = t >> 6;
    const int rm = (w >> 1) * 64, cn = (w & 1) * 64;
    const int lr = l & 15;
    const int kg16 = (l >> 4) * 16;

    const int jrow   = l >> 3;
    const int srcoff = ((l & 7) ^ jrow) << 3;

    const unsigned short* gA = Ab + (long)(m0 + jrow) * K + srcoff;
    const unsigned short* gB = Bb + (long)(n0 + jrow) * K + srcoff;

    f32x4 acc[4][4];
    #pragma unroll
    for (int i = 0; i < 4; ++i)
        #pragma unroll
        for (int j = 0; j < 4; ++j)
            acc[i][j] = (f32x4){0.f, 0.f, 0.f, 0.f};

    const int nt = K >> 6;   // requires nt >= 3

    // prologue: stage tiles 0 -> buf0, 1 -> buf1
    #pragma unroll
    for (int i = 0; i < 4; ++i) {
        const int c = w * 4 + i;
        gl16(gA + (long)(8 * c) * K, &lds[0][0][c * 512]);
        gl16(gB + (long)(8 * c) * K, &lds[0][1][c * 512]);
    }
    #pragma unroll
    for (int i = 0; i < 4; ++i) {
        const int c = w * 4 + i;
        gl16(gA + (long)(8 * c) * K + 64, &lds[1][0][c * 512]);
        gl16(gB + (long)(8 * c) * K + 64, &lds[1][1][c * 512]);
    }
    asm volatile("s_waitcnt vmcnt(8)" ::: "memory");
    __builtin_amdgcn_s_barrier();
    __builtin_amdgcn_sched_barrier(0);

    for (int it = 0; it < nt; ++it) {
        const int rb = it % 3;
        if (it + 2 < nt) {
            const int sb = (it + 2) % 3;
            const unsigned short* nA = gA + (it + 2) * 64;
            const unsigned short* nB = gB + (it + 2) * 64;
            #pragma unroll
            for (int i = 0; i < 4; ++i) {
                const int c = w * 4 + i;
                gl16(nA + (long)(8 * c) * K, &lds[sb][0][c * 512]);
                gl16(nB + (long)(8 * c) * K, &lds[sb][1][c * 512]);
            }
        }
        const char* baseA = (const char*)&lds[rb][0][0];
        const char* baseB = (const char*)&lds[rb][1][0];
        h16x8 af[2][4], bf[2][4];
        #pragma unroll
        for (int ks = 0; ks < 2; ++ks)
            #pragma unroll
            for (int mi = 0; mi < 4; ++mi) {
                const int row = rm + mi * 16 + lr;
                af[ks][mi] = *(const h16x8*)(baseA + row * 128 +
                                ((ks * 64 + kg16) ^ ((row & 7) << 4)));
            }
        #pragma unroll
        for (int ks = 0; ks < 2; ++ks)
            #pragma unroll
            for (int nj = 0; nj < 4; ++nj) {
                const int row = cn + nj * 16 + lr;
                bf[ks][nj] = *(const h16x8*)(baseB + row * 128 +
                                ((ks * 64 + kg16) ^ ((row & 7) << 4)));
            }
        __builtin_amdgcn_s_setprio(1);
        #pragma unroll
        for (int ks = 0; ks < 2; ++ks)
            #pragma unroll
            for (int mi = 0; mi < 4; ++mi)
                #pragma unroll
                for (int nj = 0; nj < 4; ++nj)
                    acc[mi][nj] = __builtin_amdgcn_mfma_f32_16x16x32_f16(
                        af[ks][mi], bf[ks][nj], acc[mi][nj], 0, 0, 0);
        __builtin_amdgcn_s_setprio(0);
        if (it + 1 < nt) {
            if (it + 2 < nt)
                asm volatile("s_waitcnt vmcnt(8)" ::: "memory");
            else
                asm volatile("s_waitcnt vmcnt(0)" ::: "memory");
            __builtin_amdgcn_s_barrier();
            __builtin_amdgcn_sched_barrier(0);
        }
    }

    #pragma unroll
    for (int mi = 0; mi < 4; ++mi) {
        #pragma unroll
        for (int nj = 0; nj < 4; ++nj) {
            const int row = m0 + rm + mi * 16 + (l >> 4) * 4;
            const int col = n0 + cn + nj * 16 + lr;
            #pragma unroll
            for (int r = 0; r < 4; ++r)
                Cb[(long)(row + r) * N + col] = acc[mi][nj][r];
        }
    }
}

// ============================================================================
// pv_2ph: 2-phase dbuf fp16 NT GEMM (kept for fp32-logit path).
// ============================================================================
__global__ __launch_bounds__(256, 1) void pv_2ph(
    const unsigned short* __restrict__ A, const unsigned short* __restrict__ Bm,
    float* __restrict__ C, int M, int N, int K,
    long strideA, long strideB, long strideC)
{
    __shared__ unsigned short lds[2][2][128 * 64];

    const int bz = blockIdx.z;
    const unsigned short* Ab = A  + (long)bz * strideA;
    const unsigned short* Bb = Bm + (long)bz * strideB;
    float* Cb = C + (long)bz * strideC;
    const int m0 = blockIdx.x * 128, n0 = blockIdx.y * 128;

    const int t = threadIdx.x;
    const int l = t & 63, w = t >> 6;
    const int rm = (w >> 1) * 64, cn = (w & 1) * 64;
    const int lr = l & 15;
    const int kg16 = (l >> 4) * 16;

    const int jrow   = l >> 3;
    const int srcoff = ((l & 7) ^ jrow) << 3;

    const unsigned short* gA = Ab + (long)(m0 + jrow) * K + srcoff;
    const unsigned short* gB = Bb + (long)(n0 + jrow) * K + srcoff;

    f32x4 acc[4][4];
    #pragma unroll
    for (int i = 0; i < 4; ++i)
        #pragma unroll
        for (int j = 0; j < 4; ++j)
            acc[i][j] = (f32x4){0.f, 0.f, 0.f, 0.f};

    const int nt = K >> 6;
    #pragma unroll
    for (int i = 0; i < 4; ++i) {
        const int c = w * 4 + i;
        gl16(gA + (long)(8 * c) * K, &lds[0][0][c * 512]);
        gl16(gB + (long)(8 * c) * K, &lds[0][1][c * 512]);
    }
    __syncthreads();

    int p = 0;
    for (int it = 0; it < nt; ++it) {
        if (it + 1 < nt) {
            const unsigned short* nA = gA + (it + 1) * 64;
            const unsigned short* nB = gB + (it + 1) * 64;
            #pragma unroll
            for (int i = 0; i < 4; ++i) {
                const int c = w * 4 + i;
                gl16(nA + (long)(8 * c) * K, &lds[p ^ 1][0][c * 512]);
                gl16(nB + (long)(8 * c) * K, &lds[p ^ 1][1][c * 512]);
            }
        }
        const char* baseA = (const char*)&lds[p][0][0];
        const char* baseB = (const char*)&lds[p][1][0];
        h16x8 af[2][4], bf[2][4];
        #pragma unroll
        for (int ks = 0; ks < 2; ++ks)
            #pragma unroll
            for (int mi = 0; mi < 4; ++mi) {
                const int row = rm + mi * 16 + lr;
                af[ks][mi] = *(const h16x8*)(baseA + row * 128 +
                                ((ks * 64 + kg16) ^ ((row & 7) << 4)));
            }
        #pragma unroll
        for (int ks = 0; ks < 2; ++ks)
            #pragma unroll
            for (int nj = 0; nj < 4; ++nj) {
                const int row = cn + nj * 16 + lr;
                bf[ks][nj] = *(const h16x8*)(baseB + row * 128 +
                                ((ks * 64 + kg16) ^ ((row & 7) << 4)));
            }
        #pragma unroll
        for (int ks = 0; ks < 2; ++ks)
            #pragma unroll
            for (int mi = 0; mi < 4; ++mi)
                #pragma unroll
                for (int nj = 0; nj < 4; ++nj)
                    acc[mi][nj] = __builtin_amdgcn_mfma_f32_16x16x32_f16(
                        af[ks][mi], bf[ks][nj], acc[mi][nj], 0, 0, 0);
        __syncthreads();
        p ^= 1;
    }

    #pragma unroll
    for (int mi = 0; mi < 4; ++mi) {
        #pragma unroll
        for (int nj = 0; nj < 4; ++nj) {
            const int row = m0 + rm + mi * 16 + (l >> 4) * 4;
            const int col = n0 + cn + nj * 16 + lr;
            #pragma unroll
            for (int r = 0; r < 4; ++r)
                Cb[(long)(row + r) * N + col] = acc[mi][nj][r];
        }
    }
}

// ============================================================================
// Generic fp32-input GEMM (KW precompute + fallback paths) - bf16 internals
// ============================================================================
template<int SPLIT, bool TRANSB, bool BIAS>
__global__ __launch_bounds__(256, 1) void mfma_gemm(
    const float* __restrict__ A, const float* __restrict__ Bsrc,
    const float* __restrict__ bias, float* __restrict__ C,
    int M, int N, int K, long strideA, long strideB, long strideC)
{
    constexpr int NB = (SPLIT > 1) ? 2 : 1;
    __shared__ unsigned short sA[NB][128 * 32];
    __shared__ unsigned short sB[NB][128 * 32];

    const int t  = threadIdx.x;
    const int bz = blockIdx.z;
    const float* Ab = A    + (long)bz * strideA;
    const float* Bb = Bsrc + (long)bz * strideB;
    float*       Cb = C    + (long)bz * strideC;
    const int m0 = blockIdx.y * 128;
    const int n0 = blockIdx.x * 128;

    const int l  = t & 63, w = t >> 6;
    const int rm = (w >> 1) * 64;
    const int cn = (w & 1) * 64;
    const int lr = l & 15;
    const int kg = (l >> 4) * 16;

    const int srow = t >> 1;
    const int skh  = (t & 1) * 16;
    const int s_ = t & 15;
    const int kp = t >> 4;

    f32x4 acc[4][4];
    #pragma unroll
    for (int i = 0; i < 4; ++i)
        #pragma unroll
        for (int j = 0; j < 4; ++j)
            acc[i][j] = (f32x4){0.f, 0.f, 0.f, 0.f};

    for (int kt = 0; kt < K; kt += 32) {
        {
            const float* p = &Ab[(long)(m0 + srow) * K + kt + skh];
            float f[16];
            #pragma unroll
            for (int q = 0; q < 4; ++q) {
                const float4 v = *(const float4*)(p + 4 * q);
                f[4*q+0] = v.x; f[4*q+1] = v.y; f[4*q+2] = v.z; f[4*q+3] = v.w;
            }
            s16x8 h0, h1, l0, l1;
            #pragma unroll
            for (int q = 0; q < 8; ++q) {
                unsigned short h = f2bf(f[q]);      h0[q] = (short)h;
                if (SPLIT > 1) l0[q] = (short)f2bf(f[q] - bf2f(h));
                unsigned short g = f2bf(f[8 + q]);  h1[q] = (short)g;
                if (SPLIT > 1) l1[q] = (short)f2bf(f[8 + q] - bf2f(g));
            }
            *(s16x8*)((char*)sA[0] + swz(srow, skh * 2))      = h0;
            *(s16x8*)((char*)sA[0] + swz(srow, skh * 2 + 16)) = h1;
            if (SPLIT > 1) {
                *(s16x8*)((char*)sA[1] + swz(srow, skh * 2))      = l0;
                *(s16x8*)((char*)sA[1] + swz(srow, skh * 2 + 16)) = l1;
            }
        }
        if (!TRANSB) {
            const float* p = &Bb[(long)(n0 + srow) * K + kt + skh];
            float f[16];
            #pragma unroll
            for (int q = 0; q < 4; ++q) {
                const float4 v = *(const float4*)(p + 4 * q);
                f[4*q+0] = v.x; f[4*q+1] = v.y; f[4*q+2] = v.z; f[4*q+3] = v.w;
            }
            s16x8 h0, h1, l0, l1;
            #pragma unroll
            for (int q = 0; q < 8; ++q) {
                unsigned short h = f2bf(f[q]);      h0[q] = (short)h;
                if (SPLIT > 1) l0[q] = (short)f2bf(f[q] - bf2f(h));
                unsigned short g = f2bf(f[8 + q]);  h1[q] = (short)g;
                if (SPLIT > 1) l1[q] = (short)f2bf(f[8 + q] - bf2f(g));
            }
            *(s16x8*)((char*)sB[0] + swz(srow, skh * 2))      = h0;
            *(s16x8*)((char*)sB[0] + swz(srow, skh * 2 + 16)) = h1;
            if (SPLIT > 1) {
                *(s16x8*)((char*)sB[1] + swz(srow, skh * 2))      = l0;
                *(s16x8*)((char*)sB[1] + swz(srow, skh * 2 + 16)) = l1;
            }
        } else {
            const float* r0 = &Bb[(long)(kt + 2 * kp) * N + n0 + s_ * 8];
            const float* r1 = r0 + N;
            float a0[8], a1[8];
            {
                const float4 u0 = *(const float4*)(r0);
                const float4 u1 = *(const float4*)(r0 + 4);
                const float4 v0 = *(const float4*)(r1);
                const float4 v1 = *(const float4*)(r1 + 4);
                a0[0]=u0.x;a0[1]=u0.y;a0[2]=u0.z;a0[3]=u0.w;
                a0[4]=u1.x;a0[5]=u1.y;a0[6]=u1.z;a0[7]=u1.w;
                a1[0]=v0.x;a1[1]=v0.y;a1[2]=v0.z;a1[3]=v0.w;
                a1[4]=v1.x;a1[5]=v1.y;a1[6]=v1.z;a1[7]=v1.w;
            }
            #pragma unroll
            for (int j = 0; j < 8; ++j) {
                const int i  = (j + s_) & 7;
                const int nl = s_ * 8 + i;
                const unsigned int val =
                    (unsigned int)f2bf(a0[i]) | ((unsigned int)f2bf(a1[i]) << 16);
                *(unsigned int*)((char*)sB[0] + swz(nl, 4 * kp)) = val;
            }
        }
        __syncthreads();

        s16x8 ah[4], bh[4];
        #pragma unroll
        for (int mi = 0; mi < 4; ++mi)
            ah[mi] = *(const s16x8*)((const char*)sA[0] + swz(rm + mi * 16 + lr, kg));
        #pragma unroll
        for (int nj = 0; nj < 4; ++nj)
            bh[nj] = *(const s16x8*)((const char*)sB[0] + swz(cn + nj * 16 + lr, kg));
        #pragma unroll
        for (int mi = 0; mi < 4; ++mi)
            #pragma unroll
            for (int nj = 0; nj < 4; ++nj)
                acc[mi][nj] = __builtin_amdgcn_mfma_f32_16x16x32_bf16(
                    ah[mi], bh[nj], acc[mi][nj], 0, 0, 0);
        if (SPLIT > 1) {
            s16x8 al[4], bl[4];
            #pragma unroll
            for (int mi = 0; mi < 4; ++mi)
                al[mi] = *(const s16x8*)((const char*)sA[1] + swz(rm + mi * 16 + lr, kg));
            #pragma unroll
            for (int mi = 0; mi < 4; ++mi)
                #pragma unroll
                for (int nj = 0; nj < 4; ++nj)
                    acc[mi][nj] = __builtin_amdgcn_mfma_f32_16x16x32_bf16(
                        al[mi], bh[nj], acc[mi][nj], 0, 0, 0);
            #pragma unroll
            for (int nj = 0; nj < 4; ++nj)
                bl[nj] = *(const s16x8*)((const char*)sB[1] + swz(cn + nj * 16 + lr, kg));
            #pragma unroll
            for (int mi = 0; mi < 4; ++mi)
                #pragma unroll
                for (int nj = 0; nj < 4; ++nj)
                    acc[mi][nj] = __builtin_amdgcn_mfma_f32_16x16x32_bf16(
                        ah[mi], bl[nj], acc[mi][nj], 0, 0, 0);
        }
        __syncthreads();
    }

    #pragma unroll
    for (int mi = 0; mi < 4; ++mi) {
        #pragma unroll
        for (int nj = 0; nj < 4; ++nj) {
            const int row = m0 + rm + mi * 16 + (l >> 4) * 4;
            const int col = n0 + cn + nj * 16 + lr;
            const float badd = BIAS ? bias[col] : 0.f;
            #pragma unroll
            for (int r = 0; r < 4; ++r)
                Cb[(long)(row + r) * N + col] = acc[mi][nj][r] + badd;
        }
    }
}

// ============================================================================
// score_gemm (bf16 3-pass) + out_gemm (fallback paths, unchanged)
// ============================================================================
__global__ __launch_bounds__(256, 1) void score_gemm(
    const unsigned short* __restrict__ Ah, const unsigned short* __restrict__ Al,
    const unsigned short* __restrict__ Bh, const unsigned short* __restrict__ Bl,
    const float* __restrict__ bias, float* __restrict__ C,
    int M, int N, int K, int nbx)
{
    __shared__ unsigned short sAh[128 * 32];
    __shared__ unsigned short sBh[128 * 32];
    __shared__ unsigned short sAl[128 * 32];
    __shared__ unsigned short sBl[128 * 32];

    const int bid = blockIdx.x;
    const int cpx = gridDim.x >> 3;
    const int sw  = (bid & 7) * cpx + (bid >> 3);
    const int mb  = sw / nbx, nb = sw % nbx;
    const int m0 = mb * 128, n0 = nb * 128;

    const int t = threadIdx.x;
    const int l = t & 63, w = t >> 6;
    const int rm = (w >> 1) * 64;
    const int cn = (w & 1) * 64;
    const int lr = l & 15;
    const int kg = (l >> 4) * 16;

    const int r0 = 2 * w, r1 = 2 * w + 1;
    const int rowS0 = 16 * r0 + (l >> 2);
    const int rowS1 = 16 * r1 + (l >> 2);
    const int h0 = (l & 3) ^ ((rowS0 >> 1) & 3);
    const int h1 = (l & 3) ^ ((rowS1 >> 1) & 3);

    const unsigned short* gAh0 = Ah + (long)(m0 + rowS0) * K + 8 * h0;
    const unsigned short* gAh1 = Ah + (long)(m0 + rowS1) * K + 8 * h1;
    const unsigned short* gAl0 = Al + (long)(m0 + rowS0) * K + 8 * h0;
    const unsigned short* gAl1 = Al + (long)(m0 + rowS1) * K + 8 * h1;
    const unsigned short* gBh0 = Bh + (long)(n0 + rowS0) * K + 8 * h0;
    const unsigned short* gBh1 = Bh + (long)(n0 + rowS1) * K + 8 * h1;
    const unsigned short* gBl0 = Bl + (long)(n0 + rowS0) * K + 8 * h0;
    const unsigned short* gBl1 = Bl + (long)(n0 + rowS1) * K + 8 * h1;

    unsigned short* dA0 = &sAh[r0 * 512];
    unsigned short* dA1 = &sAh[r1 * 512];
    unsigned short* dAl0 = &sAl[r0 * 512];
    unsigned short* dAl1 = &sAl[r1 * 512];
    unsigned short* dB0 = &sBh[r0 * 512];
    unsigned short* dB1 = &sBh[r1 * 512];
    unsigned short* dBl0 = &sBl[r0 * 512];
    unsigned short* dBl1 = &sBl[r1 * 512];

    f32x4 acc[4][4];
    #pragma unroll
    for (int i = 0; i < 4; ++i)
        #pragma unroll
        for (int j = 0; j < 4; ++j)
            acc[i][j] = (f32x4){0.f, 0.f, 0.f, 0.f};

    const int nk = K >> 5;
    for (int it = 0; it < nk; ++it) {
        gl16(gAh0, dA0);  gl16(gAh1, dA1);
        gl16(gBh0, dB0);  gl16(gBh1, dB1);
        gl16(gAl0, dAl0); gl16(gAl1, dAl1);
        gl16(gBl0, dBl0); gl16(gBl1, dBl1);
        gAh0 += 32; gAh1 += 32; gAl0 += 32; gAl1 += 32;
        gBh0 += 32; gBh1 += 32; gBl0 += 32; gBl1 += 32;
        __syncthreads();

        s16x8 ah[4], bh[4];
        #pragma unroll
        for (int mi = 0; mi < 4; ++mi)
            ah[mi] = *(const s16x8*)((const char*)sAh + swz(rm + mi * 16 + lr, kg));
        #pragma unroll
        for (int nj = 0; nj < 4; ++nj)
            bh[nj] = *(const s16x8*)((const char*)sBh + swz(cn + nj * 16 + lr, kg));
        #pragma unroll
        for (int mi = 0; mi < 4; ++mi)
            #pragma unroll
            for (int nj = 0; nj < 4; ++nj)
                acc[mi][nj] = __builtin_amdgcn_mfma_f32_16x16x32_bf16(
                    ah[mi], bh[nj], acc[mi][nj], 0, 0, 0);
        s16x8 al[4], bl[4];
        #pragma unroll
        for (int mi = 0; mi < 4; ++mi)
            al[mi] = *(const s16x8*)((const char*)sAl + swz(rm + mi * 16 + lr, kg));
        #pragma unroll
        for (int mi = 0; mi < 4; ++mi)
            #pragma unroll
            for (int nj = 0; nj < 4; ++nj)
                acc[mi][nj] = __builtin_amdgcn_mfma_f32_16x16x32_bf16(
                    al[mi], bh[nj], acc[mi][nj], 0, 0, 0);
        #pragma unroll
        for (int nj = 0; nj < 4; ++nj)
            bl[nj] = *(const s16x8*)((const char*)sBl + swz(cn + nj * 16 + lr, kg));
        #pragma unroll
        for (int mi = 0; mi < 4; ++mi)
            #pragma unroll
            for (int nj = 0; nj < 4; ++nj)
                acc[mi][nj] = __builtin_amdgcn_mfma_f32_16x16x32_bf16(
                    ah[mi], bl[nj], acc[mi][nj], 0, 0, 0);
        __syncthreads();
    }

    #pragma unroll
    for (int mi = 0; mi < 4; ++mi) {
        #pragma unroll
        for (int nj = 0; nj < 4; ++nj) {
            const int row = m0 + rm + mi * 16 + (l >> 4) * 4;
            const int col = n0 + cn + nj * 16 + lr;
            const float badd = bias[col];
            #pragma unroll
            for (int r = 0; r < 4; ++r)
                C[(long)(row + r) * N + col] = acc[mi][nj][r] + badd;
        }
    }
}

__global__ __launch_bounds__(256, 1) void out_gemm(
    const float* __restrict__ A32, const unsigned short* __restrict__ B16,
    float* __restrict__ C, int M, int N, int K,
    long strideA, long strideB, long strideC)
{
    __shared__ unsigned short sA[128 * 32];
    __shared__ unsigned short sB[128 * 32];

    const int bz = blockIdx.z;
    const float* Ab = A32 + (long)bz * strideA;
    const unsigned short* Bb = B16 + (long)bz * strideB;
    float* Cb = C + (long)bz * strideC;
    const int m0 = blockIdx.x * 128;
    const int n0 = blockIdx.y * 128;

    const int t = threadIdx.x;
    const int l = t & 63, w = t >> 6;
    const int rm = (w >> 1) * 64;
    const int cn = (w & 1) * 64;
    const int lr = l & 15;
    const int kg = (l >> 4) * 16;

    const int r0 = 2 * w, r1 = 2 * w + 1;
    const int rowS0 = 16 * r0 + (l >> 2);
    const int rowS1 = 16 * r1 + (l >> 2);
    const int h0 = (l & 3) ^ ((rowS0 >> 1) & 3);
    const int h1 = (l & 3) ^ ((rowS1 >> 1) & 3);
    const unsigned short* gB0 = Bb + (long)(n0 + rowS0) * K + 8 * h0;
    const unsigned short* gB1 = Bb + (long)(n0 + rowS1) * K + 8 * h1;
    unsigned short* dB0 = &sB[r0 * 512];
    unsigned short* dB1 = &sB[r1 * 512];

    const int srow = t >> 1;
    const int skh  = (t & 1) * 16;
    const float* gA = &Ab[(long)(m0 + srow) * K + skh];

    f32x4 acc[4][4];
    #pragma unroll
    for (int i = 0; i < 4; ++i)
        #pragma unroll
        for (int j = 0; j < 4; ++j)
            acc[i][j] = (f32x4){0.f, 0.f, 0.f, 0.f};

    const int nk = K >> 5;
    for (int it = 0; it < nk; ++it) {
        gl16(gB0, dB0); gl16(gB1, dB1);
        gB0 += 32; gB1 += 32;
        {
            float f[16];
            #pragma unroll
            for (int q = 0; q < 4; ++q) {
                const float4 v = *(const float4*)(gA + 4 * q);
                f[4*q+0] = v.x; f[4*q+1] = v.y; f[4*q+2] = v.z; f[4*q+3] = v.w;
            }
            gA += 32;
            s16x8 v0, v1;
            #pragma unroll
            for (int q = 0; q < 8; ++q) {
                v0[q] = (short)f2bf(f[q]);
                v1[q] = (short)f2bf(f[8 + q]);
            }
            *(s16x8*)((char*)sA + swz(srow, skh * 2))      = v0;
            *(s16x8*)((char*)sA + swz(srow, skh * 2 + 16)) = v1;
        }
        __syncthreads();

        s16x8 ah[4], bh[4];
        #pragma unroll
        for (int mi = 0; mi < 4; ++mi)
            ah[mi] = *(const s16x8*)((const char*)sA + swz(rm + mi * 16 + lr, kg));
        #pragma unroll
        for (int nj = 0; nj < 4; ++nj)
            bh[nj] = *(const s16x8*)((const char*)sB + swz(cn + nj * 16 + lr, kg));
        #pragma unroll
        for (int mi = 0; mi < 4; ++mi)
            #pragma unroll
            for (int nj = 0; nj < 4; ++nj)
                acc[mi][nj] = __builtin_amdgcn_mfma_f32_16x16x32_bf16(
                    ah[mi], bh[nj], acc[mi][nj], 0, 0, 0);
        __syncthreads();
    }

    #pragma unroll
    for (int mi = 0; mi < 4; ++mi) {
        #pragma unroll
        for (int nj = 0; nj < 4; ++nj) {
            const int row = m0 + rm + mi * 16 + (l >> 4) * 4;
            const int col = n0 + cn + nj * 16 + lr;
            #pragma unroll
            for (int r = 0; r < 4; ++r)
                Cb[(long)(row + r) * N + col] = acc[mi][nj][r];
        }
    }
}

// ============================================================================
// small helper kernels
// ============================================================================
// MODE: 0 = fp32 out, 1 = bf16 out, 2 = fp16 out
template<int MODE>
__global__ __launch_bounds__(256) void transpose64(
    const float* __restrict__ in, void* __restrict__ outv,
    int R, int Cc, long sIn, long sOut)
{
    __shared__ float tl[64][65];
    const int z = blockIdx.z;
    const float* ib = in + (long)z * sIn;
    const int r0 = blockIdx.x * 64, c0 = blockIdx.y * 64;
    const int t = threadIdx.x;
    const int lrr = t >> 4, lc = (t & 15) * 4;
    #pragma unroll
    for (int p = 0; p < 4; ++p) {
        const float4 v = *(const float4*)&ib[(long)(r0 + lrr + 16 * p) * Cc + c0 + lc];
        tl[lrr + 16 * p][lc + 0] = v.x; tl[lrr + 16 * p][lc + 1] = v.y;
        tl[lrr + 16 * p][lc + 2] = v.z; tl[lrr + 16 * p][lc + 3] = v.w;
    }
    __syncthreads();
    #pragma unroll
    for (int p = 0; p < 4; ++p) {
        const int orow = c0 + lrr + 16 * p;
        const int ocol = r0 + lc;
        const float a = tl[lc + 0][lrr + 16 * p];
        const float b = tl[lc + 1][lrr + 16 * p];
        const float c = tl[lc + 2][lrr + 16 * p];
        const float d = tl[lc + 3][lrr + 16 * p];
        if (MODE == 1) {
            ushort4 u = { f2bf(a), f2bf(b), f2bf(c), f2bf(d) };
            *(ushort4*)((unsigned short*)outv + (long)z * sOut + (long)orow * R + ocol) = u;
        } else if (MODE == 2) {
            ushort4 u = { f2h(a), f2h(b), f2h(c), f2h(d) };
            *(ushort4*)((unsigned short*)outv + (long)z * sOut + (long)orow * R + ocol) = u;
        } else {
            float4 u = { a, b, c, d };
            *(float4*)((float*)outv + (long)z * sOut + (long)orow * R + ocol) = u;
        }
    }
}

// fp32 -> bf16 hi/lo (mid path)
__global__ __launch_bounds__(256) void convert_hilo(
    const float* __restrict__ src, unsigned short* __restrict__ hi,
    unsigned short* __restrict__ lo, long n8)
{
    for (long i = (long)blockIdx.x * blockDim.x + threadIdx.x; i < n8;
         i += (long)gridDim.x * blockDim.x) {
        const float4 a = *(const float4*)&src[i * 8];
        const float4 b = *(const float4*)&src[i * 8 + 4];
        const float f[8] = { a.x, a.y, a.z, a.w, b.x, b.y, b.z, b.w };
        s16x8 h, lv;
        #pragma unroll
        for (int q = 0; q < 8; ++q) {
            const unsigned short hh = f2bf(f[q]);
            h[q]  = (short)hh;
            lv[q] = (short)f2bf(f[q] - bf2f(hh));
        }
        *(s16x8*)&hi[i * 8] = h;
        *(s16x8*)&lo[i * 8] = lv;
    }
}

// fp32 [rows][Kd] -> fp16 interleaved [rows][2*Kd]: hi at col, lo at Kd+col.
__global__ __launch_bounds__(256) void convert_q_ilv(
    const float* __restrict__ src, unsigned short* __restrict__ dst,
    int kd8, long n8)   // kd8 = Kd/8
{
    const int Kd = kd8 * 8;
    for (long i = (long)blockIdx.x * blockDim.x + threadIdx.x; i < n8;
         i += (long)gridDim.x * blockDim.x) {
        const long row = i / kd8;
        const int  col = (int)(i - row * kd8) * 8;
        const float4 a = *(const float4*)&src[i * 8];
        const float4 b = *(const float4*)&src[i * 8 + 4];
        const float f[8] = { a.x, a.y, a.z, a.w, b.x, b.y, b.z, b.w };
        s16x8 h, lv;
        #pragma unroll
        for (int q = 0; q < 8; ++q) {
            const unsigned short hh = f2h(f[q]);
            h[q]  = (short)hh;
            lv[q] = (short)f2h(f[q] - h2f(hh));
        }
        unsigned short* dr = dst + row * (long)(2 * Kd);
        *(s16x8*)&dr[col]      = h;
        *(s16x8*)&dr[Kd + col] = lv;
    }
}

// fp32 [rows][Kd] -> fp16 duplicated [rows][2*Kd]: hi at col AND Kd+col.
__global__ __launch_bounds__(256) void convert_kw_dup(
    const float* __restrict__ src, unsigned short* __restrict__ dst,
    int kd8, long n8)
{
    const int Kd = kd8 * 8;
    for (long i = (long)blockIdx.x * blockDim.x + threadIdx.x; i < n8;
         i += (long)gridDim.x * blockDim.x) {
        const long row = i / kd8;
        const int  col = (int)(i - row * kd8) * 8;
        const float4 a = *(const float4*)&src[i * 8];
        const float4 b = *(const float4*)&src[i * 8 + 4];
        const float f[8] = { a.x, a.y, a.z, a.w, b.x, b.y, b.z, b.w };
        s16x8 h;
        #pragma unroll
        for (int q = 0; q < 8; ++q) h[q] = (short)f2h(f[q]);
        unsigned short* dr = dst + row * (long)(2 * Kd);
        *(s16x8*)&dr[col]      = h;
        *(s16x8*)&dr[Kd + col] = h;
    }
}

__global__ __launch_bounds__(256) void bk_dot(
    const float* __restrict__ key, const float* __restrict__ b,
    float* __restrict__ bk, int D)
{
    const int row = blockIdx.x * 4 + (threadIdx.x >> 6);
    const int l = threadIdx.x & 63;
    const float* kr = key + (long)row * D;
    float s = 0.f;
    for (int e = l; e < D; e += 64) s += kr[e] * b[e];
    #pragma unroll
    for (int off = 32; off > 0; off >>= 1) s += __shfl_xor(s, off);
    if (l == 0) bk[row] = s;
}

// Softmax from fp16 logits; writes fp32 attn + normalized fp16 IN-PLACE over
// the logit slot (exact 16B-per-thread alias, read-before-write). cols = 2048.
__global__ __launch_bounds__(256) void softmax_h16(
    unsigned short* __restrict__ L16, float* __restrict__ Afp, int cols)
{
    const long row = blockIdx.x;
    unsigned short* pl = L16 + row * (long)cols;
    float* pf = Afp + row * (long)cols;
    const int t = threadIdx.x;
    const int wid = t >> 6;
    const int base = t * 8;

    const s16x8 hv = *(const s16x8*)&pl[base];
    float vals[8];
    #pragma unroll
    for (int i = 0; i < 8; ++i) vals[i] = h2f((unsigned short)hv[i]);
    float m = -INFINITY;
    #pragma unroll
    for (int i = 0; i < 8; ++i) m = fmaxf(m, vals[i]);
    #pragma unroll
    for (int off = 32; off > 0; off >>= 1)
        m = fmaxf(m, __shfl_xor(m, off));
    __shared__ float smax[4], ssum[4];
    if ((t & 63) == 0) smax[wid] = m;
    __syncthreads();
    m = fmaxf(fmaxf(smax[0], smax[1]), fmaxf(smax[2], smax[3]));

    float s = 0.f;
    #pragma unroll
    for (int i = 0; i < 8; ++i) {
        vals[i] = __expf(vals[i] - m);
        s += vals[i];
    }
    #pragma unroll
    for (int off = 32; off > 0; off >>= 1)
        s += __shfl_xor(s, off);
    if ((t & 63) == 0) ssum[wid] = s;
    __syncthreads();
    s = (ssum[0] + ssum[1]) + (ssum[2] + ssum[3]);
    const float inv = 1.0f / s;

    float4 o0, o1;
    o0.x = vals[0]*inv; o0.y = vals[1]*inv; o0.z = vals[2]*inv; o0.w = vals[3]*inv;
    o1.x = vals[4]*inv; o1.y = vals[5]*inv; o1.z = vals[6]*inv; o1.w = vals[7]*inv;
    *(float4*)&pf[base]     = o0;
    *(float4*)&pf[base + 4] = o1;
    s16x8 h;
    h[0]=(short)f2h(o0.x); h[1]=(short)f2h(o0.y); h[2]=(short)f2h(o0.z); h[3]=(short)f2h(o0.w);
    h[4]=(short)f2h(o1.x); h[5]=(short)f2h(o1.y); h[6]=(short)f2h(o1.z); h[7]=(short)f2h(o1.w);
    *(s16x8*)&pl[base] = h;
}

// In-place row softmax + fp16 copy (fp32-logit path); cols = 2048.
__global__ __launch_bounds__(256) void softmax_f16(
    float* __restrict__ S, unsigned short* __restrict__ S16, int cols)
{
    const long row = blockIdx.x;
    float* p = S + row * (long)cols;
    unsigned short* p16 = S16 + row * (long)cols;
    const int t = threadIdx.x;
    const int wid = t >> 6;
    const int base = t * 8;

    const float4 a = *(const float4*)&p[base];
    const float4 b = *(const float4*)&p[base + 4];
    float vals[8] = { a.x, a.y, a.z, a.w, b.x, b.y, b.z, b.w };
    float m = -INFINITY;
    #pragma unroll
    for (int i = 0; i < 8; ++i) m = fmaxf(m, vals[i]);
    #pragma unroll
    for (int off = 32; off > 0; off >>= 1)
        m = fmaxf(m, __shfl_xor(m, off));
    __shared__ float smax[4], ssum[4];
    if ((t & 63) == 0) smax[wid] = m;
    __syncthreads();
    m = fmaxf(fmaxf(smax[0], smax[1]), fmaxf(smax[2], smax[3]));

    float s = 0.f;
    #pragma unroll
    for (int i = 0; i < 8; ++i) {
        vals[i] = __expf(vals[i] - m);
        s += vals[i];
    }
    #pragma unroll
    for (int off = 32; off > 0; off >>= 1)
        s += __shfl_xor(s, off);
    if ((t & 63) == 0) ssum[wid] = s;
    __syncthreads();
    s = (ssum[0] + ssum[1]) + (ssum[2] + ssum[3]);
    const float inv = 1.0f / s;

    float4 o0, o1;
    o0.x = vals[0]*inv; o0.y = vals[1]*inv; o0.z = vals[2]*inv; o0.w = vals[3]*inv;
    o1.x = vals[4]*inv; o1.y = vals[5]*inv; o1.z = vals[6]*inv; o1.w = vals[7]*inv;
    *(float4*)&p[base]     = o0;
    *(float4*)&p[base + 4] = o1;
    s16x8 h;
    h[0]=(short)f2h(o0.x); h[1]=(short)f2h(o0.y); h[2]=(short)f2h(o0.z); h[3]=(short)f2h(o0.w);
    h[4]=(short)f2h(o1.x); h[5]=(short)f2h(o1.y); h[6]=(short)f2h(o1.z); h[7]=(short)f2h(o1.w);
    *(s16x8*)&p16[base] = h;
}

// plain softmax (mid/fallback paths)
__global__ __launch_bounds__(256) void softmax_rows(float* __restrict__ S, int cols)
{
    const long row = blockIdx.x;
    float* p = S + row * (long)cols;
    const int t = threadIdx.x;
    const int wid = t >> 6;

    float vals[8];
    float m = -INFINITY;
    #pragma unroll
    for (int i = 0; i < 8; ++i) {
        vals[i] = p[t + i * 256];
        m = fmaxf(m, vals[i]);
    }
    #pragma unroll
    for (int off = 32; off > 0; off >>= 1)
        m = fmaxf(m, __shfl_xor(m, off));
    __shared__ float smax[4], ssum[4];
    if ((t & 63) == 0) smax[wid] = m;
    __syncthreads();
    m = fmaxf(fmaxf(smax[0], smax[1]), fmaxf(smax[2], smax[3]));

    float s = 0.f;
    #pragma unroll
    for (int i = 0; i < 8; ++i) {
        vals[i] = __expf(vals[i] - m);
        s += vals[i];
    }
    #pragma unroll
    for (int off = 32; off > 0; off >>= 1)
        s += __shfl_xor(s, off);
    if ((t & 63) == 0) ssum[wid] = s;
    __syncthreads();
    s = (ssum[0] + ssum[1]) + (ssum[2] + ssum[3]);
    const float inv = 1.0f / s;
    #pragma unroll
    for (int i = 0; i < 8; ++i)
        p[t + i * 256] = vals[i] * inv;
}

// ============================================================================
extern "C" void kernel_launch(void* const* d_in, const int* in_sizes, int n_in,
                              void* d_out, int out_size, void* d_ws, size_t ws_size,
                              hipStream_t stream)
{
    const float* query = (const float*)d_in[0];  // [B, Nq, D]
    const float* key   = (const float*)d_in[1];  // [Nk, D]
    const float* x     = (const float*)d_in[2];  // [B, Nk, D]
    const float* W     = (const float*)d_in[3];  // [D, D]
    const float* bias  = (const float*)d_in[4];  // [D]

    const int D  = in_sizes[4];                  // 768
    const int Nk = in_sizes[1] / D;              // 2048
    const int B  = in_sizes[2] / (Nk * D);       // 8
    const int Nq = in_sizes[0] / (B * D);        // 2048

    float* out  = (float*)d_out;                 // [B, Nq, D]
    float* attn = out + (long)B * Nq * D;        // [B, Nq, Nk]

    const long nQ  = (long)B * Nq * D;           // 12,582,912
    const long nKW = (long)Nk * D;               // 1,572,864
    const long nX  = (long)B * Nk * D;           // 12,582,912
    const int  M   = B * Nq;                     // 16384
    const int  K2  = 2 * D;                      // 1536

    const size_t xTb    = (size_t)nX * 2;                // 25.2 MB
    const size_t kwDupB = (size_t)Nk * K2 * 2;           // 6.3 MB
    const size_t bkB    = (size_t)Nk * 4;                // 8 KB
    const size_t atb1   = (size_t)Nq * Nk * 2;           // 8.39 MB per batch
    const size_t fixedB = xTb + kwDupB + bkB;            // ~31.5 MB
    const size_t qLob   = (size_t)nQ * 2;
    const size_t wsMid  = xTb + qLob;                    // 50.3 MB (mid path)
    const size_t wsF16  = fixedB + 4 * atb1;             // ~65.1 MB (fp16-logit path)

    int g = 0;
    if (ws_size >= fixedB + 2 * atb1) {
        g = (int)((ws_size - fixedB) / atb1);
        if (g > B) g = B;
    }

    if (ws_size >= wsF16 && B == 8) {
        // ----- fastest path: fp16 logits, 4-batch slot, 2 full-fill score launches -----
        unsigned short* qIlv  = (unsigned short*)out;   // out region scratch
        unsigned short* xT    = (unsigned short*)d_ws;
        unsigned short* kwDup = (unsigned short*)((char*)d_ws + xTb);
        float*          bk    = (float*)((char*)d_ws + xTb + kwDupB);
        unsigned short* slot  = (unsigned short*)((char*)d_ws + fixedB);  // 4 batches
        float* Wt  = attn;                              // attn region scratch
        float* KWf = attn + 1048576;

        dim3 gtw(D / 64, D / 64, 1);
        transpose64<0><<<gtw, 256, 0, stream>>>(W, Wt, D, D, 0L, 0L);
        dim3 gkw(D / 128, Nk / 128, 1);
        mfma_gemm<3, false, false><<<gkw, 256, 0, stream>>>(
            key, Wt, nullptr, KWf, Nk, D, D, 0L, 0L, 0L);
        convert_kw_dup<<<768, 256, 0, stream>>>(KWf, kwDup, D / 8, nKW / 8);
        bk_dot<<<Nk / 4, 256, 0, stream>>>(key, bias, bk, D);
        convert_q_ilv<<<2048, 256, 0, stream>>>(query, qIlv, D / 8, nQ / 8);
        dim3 gtx(Nk / 64, D / 64, B);
        transpose64<2><<<gtx, 256, 0, stream>>>(
            x, xT, Nk, D, (long)Nk * D, (long)D * Nk);

        const int nbx = Nk / 256;                        // 8
        for (int grp = 0; grp < 2; ++grp) {
            const int b0 = grp * 4;
            const int nwg = (4 * Nq / 256) * nbx;        // 256 = full fill
            score_8ph<1><<<nwg, 512, 0, stream>>>(
                qIlv + (long)b0 * Nq * K2, kwDup, bk, slot, 4 * Nq, Nk, K2, nbx);
            softmax_h16<<<4 * Nq, 256, 0, stream>>>(
                slot, attn + (long)b0 * Nq * Nk, Nk);
            dim3 go(Nq / 128, D / 128, 4);
            pv_ring<<<go, 256, 0, stream>>>(
                slot, xT + (long)b0 * D * Nk, out + (long)b0 * Nq * D,
                Nq, D, Nk, (long)Nq * Nk, (long)D * Nk, (long)Nq * D);
        }
    } else if (g >= 2) {
        // ----- fp32-logit fast path -----
        unsigned short* qIlv  = (unsigned short*)out;
        unsigned short* xT     = (unsigned short*)d_ws;
        unsigned short* kwDup  = (unsigned short*)((char*)d_ws + xTb);
        float*          bk     = (float*)((char*)d_ws + xTb + kwDupB);
        unsigned short* attn16 = (unsigned short*)((char*)d_ws + fixedB);
        float* Wt  = attn;
        float* KWf = attn + 1048576;

        dim3 gtw(D / 64, D / 64, 1);
        transpose64<0><<<gtw, 256, 0, stream>>>(W, Wt, D, D, 0L, 0L);
        dim3 gkw(D / 128, Nk / 128, 1);
        mfma_gemm<3, false, false><<<gkw, 256, 0, stream>>>(
            key, Wt, nullptr, KWf, Nk, D, D, 0L, 0L, 0L);
        convert_kw_dup<<<768, 256, 0, stream>>>(KWf, kwDup, D / 8, nKW / 8);
        bk_dot<<<Nk / 4, 256, 0, stream>>>(key, bias, bk, D);
        convert_q_ilv<<<2048, 256, 0, stream>>>(query, qIlv, D / 8, nQ / 8);
        dim3 gtx(Nk / 64, D / 64, B);
        transpose64<2><<<gtx, 256, 0, stream>>>(
            x, xT, Nk, D, (long)Nk * D, (long)D * Nk);

        const int nbx = Nk / 256;                        // 8
        const int nwg = (M / 256) * nbx;                 // 512
        score_8ph<0><<<nwg, 512, 0, stream>>>(
            qIlv, kwDup, bk, attn, M, Nk, K2, nbx);

        for (int b0 = 0; b0 < B; b0 += g) {
            const int gb = (b0 + g <= B) ? g : (B - b0);
            softmax_f16<<<gb * Nq, 256, 0, stream>>>(
                attn + (long)b0 * Nq * Nk, attn16, Nk);
            dim3 go(Nq / 128, D / 128, gb);
            pv_2ph<<<go, 256, 0, stream>>>(
                attn16, xT + (long)b0 * D * Nk, out + (long)b0 * Nq * D,
                Nq, D, Nk, (long)Nq * Nk, (long)D * Nk, (long)Nq * D);
        }
    } else if (ws_size >= wsMid) {
        // ---------------- mid path (bf16 3-pass) ----------------
        unsigned short* q_hi  = (unsigned short*)out;
        unsigned short* KW_hi = q_hi + nQ;
        unsigned short* KW_lo = KW_hi + nKW;
        float*          bk    = (float*)(KW_lo + nKW);
        unsigned short* q_lo  = (unsigned short*)d_ws;
        unsigned short* xT    = q_lo + nQ;
        float* Wt  = attn;
        float* KWf = attn + 1048576;

        dim3 gtw(D / 64, D / 64, 1);
        transpose64<0><<<gtw, 256, 0, stream>>>(W, Wt, D, D, 0L, 0L);
        dim3 gkw(D / 128, Nk / 128, 1);
        mfma_gemm<3, false, false><<<gkw, 256, 0, stream>>>(
            key, Wt, nullptr, KWf, Nk, D, D, 0L, 0L, 0L);
        convert_hilo<<<768, 256, 0, stream>>>(KWf, KW_hi, KW_lo, nKW / 8);
        bk_dot<<<Nk / 4, 256, 0, stream>>>(key, bias, bk, D);
        convert_hilo<<<2048, 256, 0, stream>>>(query, q_hi, q_lo, nQ / 8);
        dim3 gtx(Nk / 64, D / 64, B);
        transpose64<1><<<gtx, 256, 0, stream>>>(
            x, xT, Nk, D, (long)Nk * D, (long)D * Nk);
        const int nbx = Nk / 128;
        const int nwg = (B * Nq / 128) * nbx;
        score_gemm<<<nwg, 256, 0, stream>>>(
            q_hi, q_lo, KW_hi, KW_lo, bk, attn, B * Nq, Nk, D, nbx);
        softmax_rows<<<B * Nq, 256, 0, stream>>>(attn, Nk);
        dim3 go(Nq / 128, D / 128, B);
        out_gemm<<<go, 256, 0, stream>>>(
            attn, xT, out, Nq, D, Nk, (long)Nq * Nk, (long)D * Nk, (long)Nq * D);
    } else {
        // ---------------- round-2 fallback ----------------
        float* qp = out;
        dim3 g1(D / 128, (B * Nq) / 128, 1);
        mfma_gemm<3, false, true><<<g1, 256, 0, stream>>>(
            query, W, bias, qp, B * Nq, D, D, 0L, 0L, 0L);
        dim3 g2(Nk / 128, Nq / 128, B);
        mfma_gemm<3, false, false><<<g2, 256, 0, stream>>>(
            qp, key, nullptr, attn, Nq, Nk, D, (long)Nq * D, 0L, (long)Nq * Nk);
        softmax_rows<<<B * Nq, 256, 0, stream>>>(attn, Nk);
        dim3 g4(D / 128, Nq / 128, B);
        mfma_gemm<1, true, false><<<g4, 256, 0, stream>>>(
            attn, x, nullptr, out, Nq, D, Nk, (long)Nq * Nk, (long)Nk * D, (long)Nq * D);
    }
}

// Round 13
// 308.443 us; speedup vs baseline: 1.0973x; 1.0973x over previous
//
#include <hip/hip_runtime.h>

typedef short s16x8 __attribute__((ext_vector_type(8)));     // 8x 16-bit in 4 VGPRs
typedef _Float16 h16x8 __attribute__((ext_vector_type(8)));  // 8 fp16 in 4 VGPRs
typedef float f32x4 __attribute__((ext_vector_type(4)));

__device__ __forceinline__ unsigned short f2bf(float f) {
    unsigned int u = __builtin_bit_cast(unsigned int, f);
    u += 0x7FFFu + ((u >> 16) & 1u);           // round-to-nearest-even
    return (unsigned short)(u >> 16);
}
__device__ __forceinline__ float bf2f(unsigned short h) {
    unsigned int u = ((unsigned int)h) << 16;
    return __builtin_bit_cast(float, u);
}
__device__ __forceinline__ unsigned short f2h(float f) {
    _Float16 h = (_Float16)f;                  // v_cvt_f16_f32, RNE
    return __builtin_bit_cast(unsigned short, h);
}
__device__ __forceinline__ float h2f(unsigned short u) {
    return (float)__builtin_bit_cast(_Float16, u);
}

// legacy swizzle for the [128][32] tiles (fallback kernels)
__device__ __forceinline__ int swz(int row, int kbyte) {
    return (row * 64 + kbyte) ^ (((row >> 1) & 3) << 4);
}

// async global->LDS, 16B per lane; LDS dest is wave-uniform base + lane*16.
__device__ __forceinline__ void gl16(const void* g, void* l) {
    __builtin_amdgcn_global_load_lds(
        (__attribute__((address_space(1))) void*)(g),
        (__attribute__((address_space(3))) void*)(l), 16, 0, 0);
}

// ============================================================================
// score_8ph: 256x256 tile, BK=64, 512 threads (8 waves: 2M x 4N).
// Register-carry, SINGLE vmcnt(8)/K-tile, ONE barrier per phase, bf1 hoisted
// to P1 (round-12 hoist kept; round-12's pv_ring reverted).
// Slot ring: P2 stages A0(tau+2), P3 B0, P4 B1+A1; vmcnt(8) at P4.
// Tails: nt-2 -> vmcnt(0); nt-1 -> none.
// OUTMODE: 0 = fp32 out (+bias), 1 = fp16 out (+bias).
// ============================================================================
#define STG(ptr, rowbase, tt, bufp, slot) do {                                      \
    gl16((ptr) + (long)((rowbase) + sl) * K + (tt) * 64 + koff,                     \
         &lds[bufp][slot][(unsigned)t * 8]);                                        \
    gl16((ptr) + (long)((rowbase) + 64 + sl) * K + (tt) * 64 + koff,                \
         &lds[bufp][slot][4096u + (unsigned)t * 8]);                                \
} while (0)

#define LDA(qi_) do {                                                               \
    const char* ba_ = (const char*)&lds[bp][qi_][0];                                \
    _Pragma("unroll")                                                               \
    for (int ks_ = 0; ks_ < 2; ++ks_)                                               \
        _Pragma("unroll")                                                           \
        for (int f_ = 0; f_ < 4; ++f_) {                                            \
            const int row_ = wm * 64 + f_ * 16 + lr;                                \
            af[ks_][f_] = *(const h16x8*)(ba_ + row_ * 128 +                        \
                            ((ks_ * 64 + kg16) ^ ((row_ & 7) << 4)));               \
        }                                                                           \
} while (0)

#define LDB(dst_, qj_) do {                                                         \
    const char* bb_ = (const char*)&lds[bp][2 + (qj_)][0];                          \
    _Pragma("unroll")                                                               \
    for (int ks_ = 0; ks_ < 2; ++ks_)                                               \
        _Pragma("unroll")                                                           \
        for (int g_ = 0; g_ < 2; ++g_) {                                            \
            const int row_ = wn * 32 + g_ * 16 + lr;                                \
            dst_[ks_][g_] = *(const h16x8*)(bb_ + row_ * 128 +                      \
                            ((ks_ * 64 + kg16) ^ ((row_ & 7) << 4)));               \
        }                                                                           \
} while (0)

#define BARR() do {                                                                 \
    __builtin_amdgcn_s_barrier();                                                   \
    __builtin_amdgcn_sched_barrier(0);                                              \
} while (0)

// MFMA cluster without trailing barrier
#define MMNB(qi_, qj_, bfv_) do {                                                   \
    __builtin_amdgcn_s_setprio(1);                                                  \
    _Pragma("unroll")                                                               \
    for (int ks_ = 0; ks_ < 2; ++ks_)                                               \
        _Pragma("unroll")                                                           \
        for (int f_ = 0; f_ < 4; ++f_)                                              \
            _Pragma("unroll")                                                       \
            for (int g_ = 0; g_ < 2; ++g_)                                          \
                acc[qi_][qj_][f_][g_] = __builtin_amdgcn_mfma_f32_16x16x32_f16(     \
                    af[ks_][f_], bfv_[ks_][g_], acc[qi_][qj_][f_][g_], 0, 0, 0);    \
    __builtin_amdgcn_s_setprio(0);                                                  \
} while (0)

template<int F16OUT>
__global__ __launch_bounds__(512, 2) void score_8ph(
    const unsigned short* __restrict__ A, const unsigned short* __restrict__ Bm,
    const float* __restrict__ bias, void* __restrict__ Cv,
    int M, int N, int K, int nbx)
{
    __shared__ unsigned short lds[2][4][8192];   // [buf][slot A0,A1,B0,B1] 128 KiB

    const int bid = blockIdx.x;
    const int cpx = gridDim.x >> 3;
    const int sw  = (bid & 7) * cpx + (bid >> 3);   // XCD-contiguous remap
    const int m0 = (sw / nbx) * 256, n0 = (sw % nbx) * 256;

    const int t = threadIdx.x;
    const int l = t & 63, w = t >> 6;
    const int wm = w >> 2, wn = w & 3;
    const int lr = l & 15;
    const int kg16 = (l >> 4) * 16;

    const int sl   = w * 8 + (l >> 3);           // 0..63
    const int koff = ((l & 7) ^ (sl & 7)) * 8;   // inverse-swizzle src k-offset (elems)

    h16x8 af[2][4], bf0[2][2], bf1[2][2];
    f32x4 acc[2][2][4][2];
    #pragma unroll
    for (int a = 0; a < 2; ++a)
        #pragma unroll
        for (int b = 0; b < 2; ++b)
            #pragma unroll
            for (int c = 0; c < 4; ++c)
                #pragma unroll
                for (int d = 0; d < 2; ++d)
                    acc[a][b][c][d] = (f32x4){0.f, 0.f, 0.f, 0.f};

    const int nt = K >> 6;   // requires nt >= 3

    // prologue: stage tiles 0 (buf0) and 1 (buf1) fully; drain tile 0.
    STG(A,  m0,       0, 0, 0);
    STG(Bm, n0,       0, 0, 2);
    STG(Bm, n0 + 128, 0, 0, 3);
    STG(A,  m0 + 128, 0, 0, 1);
    STG(A,  m0,       1, 1, 0);
    STG(Bm, n0,       1, 1, 2);
    STG(Bm, n0 + 128, 1, 1, 3);
    STG(A,  m0 + 128, 1, 1, 1);
    asm volatile("s_waitcnt vmcnt(8)" ::: "memory");
    BARR();

    int tau = 0;
    for (; tau < nt - 2; ++tau) {
        const int bp = tau & 1;
        // P1 (0,0): load af0, bf0, AND bf1 (hoisted)
        LDA(0); LDB(bf0, 0); LDB(bf1, 1);
        MMNB(0, 0, bf0);
        BARR();
        // P2 (0,1): no LDS reads
        STG(A, m0, tau + 2, bp, 0);
        MMNB(0, 1, bf1);
        BARR();
        // P3 (1,1)
        LDA(1);
        STG(Bm, n0, tau + 2, bp, 2);
        MMNB(1, 1, bf1);
        BARR();
        // P4 (1,0)
        STG(Bm, n0 + 128, tau + 2, bp, 3);
        STG(A,  m0 + 128, tau + 2, bp, 1);
        asm volatile("s_waitcnt vmcnt(8)" ::: "memory");
        MMNB(1, 0, bf0);
        BARR();
    }
    {   // tile nt-2: no staging; drain at P4
        const int bp = tau & 1;
        LDA(0); LDB(bf0, 0); LDB(bf1, 1);
        MMNB(0, 0, bf0);
        BARR();
        MMNB(0, 1, bf1);
        BARR();
        LDA(1);
        MMNB(1, 1, bf1);
        BARR();
        asm volatile("s_waitcnt vmcnt(0)" ::: "memory");
        MMNB(1, 0, bf0);
        BARR();
        ++tau;
    }
    {   // tile nt-1: no staging, nothing outstanding
        const int bp = tau & 1;
        LDA(0); LDB(bf0, 0); LDB(bf1, 1);
        MMNB(0, 0, bf0);
        BARR();
        MMNB(0, 1, bf1);
        BARR();
        LDA(1);
        MMNB(1, 1, bf1);
        BARR();
        MMNB(1, 0, bf0);
    }

    // epilogue
    #pragma unroll
    for (int qi = 0; qi < 2; ++qi)
        #pragma unroll
        for (int qj = 0; qj < 2; ++qj)
            #pragma unroll
            for (int f = 0; f < 4; ++f)
                #pragma unroll
                for (int g = 0; g < 2; ++g) {
                    const int row = m0 + qi * 128 + wm * 64 + f * 16 + (l >> 4) * 4;
                    const int col = n0 + qj * 128 + wn * 32 + g * 16 + lr;
                    const float badd = bias[col];
                    if (F16OUT) {
                        unsigned short* C = (unsigned short*)Cv;
                        #pragma unroll
                        for (int r = 0; r < 4; ++r)
                            C[(long)(row + r) * N + col] =
                                f2h(acc[qi][qj][f][g][r] + badd);
                    } else {
                        float* C = (float*)Cv;
                        #pragma unroll
                        for (int r = 0; r < 4; ++r)
                            C[(long)(row + r) * N + col] = acc[qi][qj][f][g][r] + badd;
                    }
                }
}

// ============================================================================
// pv_2ph: 2-phase dbuf fp16 NT GEMM (proven; 64KB LDS -> 2 blocks/CU).
// ============================================================================
__global__ __launch_bounds__(256, 1) void pv_2ph(
    const unsigned short* __restrict__ A, const unsigned short* __restrict__ Bm,
    float* __restrict__ C, int M, int N, int K,
    long strideA, long strideB, long strideC)
{
    __shared__ unsigned short lds[2][2][128 * 64];

    const int bz = blockIdx.z;
    const unsigned short* Ab = A  + (long)bz * strideA;
    const unsigned short* Bb = Bm + (long)bz * strideB;
    float* Cb = C + (long)bz * strideC;
    const int m0 = blockIdx.x * 128, n0 = blockIdx.y * 128;

    const int t = threadIdx.x;
    const int l = t & 63, w = t >> 6;
    const int rm = (w >> 1) * 64, cn = (w & 1) * 64;
    const int lr = l & 15;
    const int kg16 = (l >> 4) * 16;

    const int jrow   = l >> 3;
    const int srcoff = ((l & 7) ^ jrow) << 3;

    const unsigned short* gA = Ab + (long)(m0 + jrow) * K + srcoff;
    const unsigned short* gB = Bb + (long)(n0 + jrow) * K + srcoff;

    f32x4 acc[4][4];
    #pragma unroll
    for (int i = 0; i < 4; ++i)
        #pragma unroll
        for (int j = 0; j < 4; ++j)
            acc[i][j] = (f32x4){0.f, 0.f, 0.f, 0.f};

    const int nt = K >> 6;
    #pragma unroll
    for (int i = 0; i < 4; ++i) {
        const int c = w * 4 + i;
        gl16(gA + (long)(8 * c) * K, &lds[0][0][c * 512]);
        gl16(gB + (long)(8 * c) * K, &lds[0][1][c * 512]);
    }
    __syncthreads();

    int p = 0;
    for (int it = 0; it < nt; ++it) {
        if (it + 1 < nt) {
            const unsigned short* nA = gA + (it + 1) * 64;
            const unsigned short* nB = gB + (it + 1) * 64;
            #pragma unroll
            for (int i = 0; i < 4; ++i) {
                const int c = w * 4 + i;
                gl16(nA + (long)(8 * c) * K, &lds[p ^ 1][0][c * 512]);
                gl16(nB + (long)(8 * c) * K, &lds[p ^ 1][1][c * 512]);
            }
        }
        const char* baseA = (const char*)&lds[p][0][0];
        const char* baseB = (const char*)&lds[p][1][0];
        h16x8 af[2][4], bf[2][4];
        #pragma unroll
        for (int ks = 0; ks < 2; ++ks)
            #pragma unroll
            for (int mi = 0; mi < 4; ++mi) {
                const int row = rm + mi * 16 + lr;
                af[ks][mi] = *(const h16x8*)(baseA + row * 128 +
                                ((ks * 64 + kg16) ^ ((row & 7) << 4)));
            }
        #pragma unroll
        for (int ks = 0; ks < 2; ++ks)
            #pragma unroll
            for (int nj = 0; nj < 4; ++nj) {
                const int row = cn + nj * 16 + lr;
                bf[ks][nj] = *(const h16x8*)(baseB + row * 128 +
                                ((ks * 64 + kg16) ^ ((row & 7) << 4)));
            }
        #pragma unroll
        for (int ks = 0; ks < 2; ++ks)
            #pragma unroll
            for (int mi = 0; mi < 4; ++mi)
                #pragma unroll
                for (int nj = 0; nj < 4; ++nj)
                    acc[mi][nj] = __builtin_amdgcn_mfma_f32_16x16x32_f16(
                        af[ks][mi], bf[ks][nj], acc[mi][nj], 0, 0, 0);
        __syncthreads();
        p ^= 1;
    }

    #pragma unroll
    for (int mi = 0; mi < 4; ++mi) {
        #pragma unroll
        for (int nj = 0; nj < 4; ++nj) {
            const int row = m0 + rm + mi * 16 + (l >> 4) * 4;
            const int col = n0 + cn + nj * 16 + lr;
            #pragma unroll
            for (int r = 0; r < 4; ++r)
                Cb[(long)(row + r) * N + col] = acc[mi][nj][r];
        }
    }
}

// ============================================================================
// Generic fp32-input GEMM (KW precompute + fallback paths) - bf16 internals
// ============================================================================
template<int SPLIT, bool TRANSB, bool BIAS>
__global__ __launch_bounds__(256, 1) void mfma_gemm(
    const float* __restrict__ A, const float* __restrict__ Bsrc,
    const float* __restrict__ bias, float* __restrict__ C,
    int M, int N, int K, long strideA, long strideB, long strideC)
{
    constexpr int NB = (SPLIT > 1) ? 2 : 1;
    __shared__ unsigned short sA[NB][128 * 32];
    __shared__ unsigned short sB[NB][128 * 32];

    const int t  = threadIdx.x;
    const int bz = blockIdx.z;
    const float* Ab = A    + (long)bz * strideA;
    const float* Bb = Bsrc + (long)bz * strideB;
    float*       Cb = C    + (long)bz * strideC;
    const int m0 = blockIdx.y * 128;
    const int n0 = blockIdx.x * 128;

    const int l  = t & 63, w = t >> 6;
    const int rm = (w >> 1) * 64;
    const int cn = (w & 1) * 64;
    const int lr = l & 15;
    const int kg = (l >> 4) * 16;

    const int srow = t >> 1;
    const int skh  = (t & 1) * 16;
    const int s_ = t & 15;
    const int kp = t >> 4;

    f32x4 acc[4][4];
    #pragma unroll
    for (int i = 0; i < 4; ++i)
        #pragma unroll
        for (int j = 0; j < 4; ++j)
            acc[i][j] = (f32x4){0.f, 0.f, 0.f, 0.f};

    for (int kt = 0; kt < K; kt += 32) {
        {
            const float* p = &Ab[(long)(m0 + srow) * K + kt + skh];
            float f[16];
            #pragma unroll
            for (int q = 0; q < 4; ++q) {
                const float4 v = *(const float4*)(p + 4 * q);
                f[4*q+0] = v.x; f[4*q+1] = v.y; f[4*q+2] = v.z; f[4*q+3] = v.w;
            }
            s16x8 h0, h1, l0, l1;
            #pragma unroll
            for (int q = 0; q < 8; ++q) {
                unsigned short h = f2bf(f[q]);      h0[q] = (short)h;
                if (SPLIT > 1) l0[q] = (short)f2bf(f[q] - bf2f(h));
                unsigned short g = f2bf(f[8 + q]);  h1[q] = (short)g;
                if (SPLIT > 1) l1[q] = (short)f2bf(f[8 + q] - bf2f(g));
            }
            *(s16x8*)((char*)sA[0] + swz(srow, skh * 2))      = h0;
            *(s16x8*)((char*)sA[0] + swz(srow, skh * 2 + 16)) = h1;
            if (SPLIT > 1) {
                *(s16x8*)((char*)sA[1] + swz(srow, skh * 2))      = l0;
                *(s16x8*)((char*)sA[1] + swz(srow, skh * 2 + 16)) = l1;
            }
        }
        if (!TRANSB) {
            const float* p = &Bb[(long)(n0 + srow) * K + kt + skh];
            float f[16];
            #pragma unroll
            for (int q = 0; q < 4; ++q) {
                const float4 v = *(const float4*)(p + 4 * q);
                f[4*q+0] = v.x; f[4*q+1] = v.y; f[4*q+2] = v.z; f[4*q+3] = v.w;
            }
            s16x8 h0, h1, l0, l1;
            #pragma unroll
            for (int q = 0; q < 8; ++q) {
                unsigned short h = f2bf(f[q]);      h0[q] = (short)h;
                if (SPLIT > 1) l0[q] = (short)f2bf(f[q] - bf2f(h));
                unsigned short g = f2bf(f[8 + q]);  h1[q] = (short)g;
                if (SPLIT > 1) l1[q] = (short)f2bf(f[8 + q] - bf2f(g));
            }
            *(s16x8*)((char*)sB[0] + swz(srow, skh * 2))      = h0;
            *(s16x8*)((char*)sB[0] + swz(srow, skh * 2 + 16)) = h1;
            if (SPLIT > 1) {
                *(s16x8*)((char*)sB[1] + swz(srow, skh * 2))      = l0;
                *(s16x8*)((char*)sB[1] + swz(srow, skh * 2 + 16)) = l1;
            }
        } else {
            const float* r0 = &Bb[(long)(kt + 2 * kp) * N + n0 + s_ * 8];
            const float* r1 = r0 + N;
            float a0[8], a1[8];
            {
                const float4 u0 = *(const float4*)(r0);
                const float4 u1 = *(const float4*)(r0 + 4);
                const float4 v0 = *(const float4*)(r1);
                const float4 v1 = *(const float4*)(r1 + 4);
                a0[0]=u0.x;a0[1]=u0.y;a0[2]=u0.z;a0[3]=u0.w;
                a0[4]=u1.x;a0[5]=u1.y;a0[6]=u1.z;a0[7]=u1.w;
                a1[0]=v0.x;a1[1]=v0.y;a1[2]=v0.z;a1[3]=v0.w;
                a1[4]=v1.x;a1[5]=v1.y;a1[6]=v1.z;a1[7]=v1.w;
            }
            #pragma unroll
            for (int j = 0; j < 8; ++j) {
                const int i  = (j + s_) & 7;
                const int nl = s_ * 8 + i;
                const unsigned int val =
                    (unsigned int)f2bf(a0[i]) | ((unsigned int)f2bf(a1[i]) << 16);
                *(unsigned int*)((char*)sB[0] + swz(nl, 4 * kp)) = val;
            }
        }
        __syncthreads();

        s16x8 ah[4], bh[4];
        #pragma unroll
        for (int mi = 0; mi < 4; ++mi)
            ah[mi] = *(const s16x8*)((const char*)sA[0] + swz(rm + mi * 16 + lr, kg));
        #pragma unroll
        for (int nj = 0; nj < 4; ++nj)
            bh[nj] = *(const s16x8*)((const char*)sB[0] + swz(cn + nj * 16 + lr, kg));
        #pragma unroll
        for (int mi = 0; mi < 4; ++mi)
            #pragma unroll
            for (int nj = 0; nj < 4; ++nj)
                acc[mi][nj] = __builtin_amdgcn_mfma_f32_16x16x32_bf16(
                    ah[mi], bh[nj], acc[mi][nj], 0, 0, 0);
        if (SPLIT > 1) {
            s16x8 al[4], bl[4];
            #pragma unroll
            for (int mi = 0; mi < 4; ++mi)
                al[mi] = *(const s16x8*)((const char*)sA[1] + swz(rm + mi * 16 + lr, kg));
            #pragma unroll
            for (int mi = 0; mi < 4; ++mi)
                #pragma unroll
                for (int nj = 0; nj < 4; ++nj)
                    acc[mi][nj] = __builtin_amdgcn_mfma_f32_16x16x32_bf16(
                        al[mi], bh[nj], acc[mi][nj], 0, 0, 0);
            #pragma unroll
            for (int nj = 0; nj < 4; ++nj)
                bl[nj] = *(const s16x8*)((const char*)sB[1] + swz(cn + nj * 16 + lr, kg));
            #pragma unroll
            for (int mi = 0; mi < 4; ++mi)
                #pragma unroll
                for (int nj = 0; nj < 4; ++nj)
                    acc[mi][nj] = __builtin_amdgcn_mfma_f32_16x16x32_bf16(
                        ah[mi], bl[nj], acc[mi][nj], 0, 0, 0);
        }
        __syncthreads();
    }

    #pragma unroll
    for (int mi = 0; mi < 4; ++mi) {
        #pragma unroll
        for (int nj = 0; nj < 4; ++nj) {
            const int row = m0 + rm + mi * 16 + (l >> 4) * 4;
            const int col = n0 + cn + nj * 16 + lr;
            const float badd = BIAS ? bias[col] : 0.f;
            #pragma unroll
            for (int r = 0; r < 4; ++r)
                Cb[(long)(row + r) * N + col] = acc[mi][nj][r] + badd;
        }
    }
}

// ============================================================================
// score_gemm (bf16 3-pass) + out_gemm (fallback paths, unchanged)
// ============================================================================
__global__ __launch_bounds__(256, 1) void score_gemm(
    const unsigned short* __restrict__ Ah, const unsigned short* __restrict__ Al,
    const unsigned short* __restrict__ Bh, const unsigned short* __restrict__ Bl,
    const float* __restrict__ bias, float* __restrict__ C,
    int M, int N, int K, int nbx)
{
    __shared__ unsigned short sAh[128 * 32];
    __shared__ unsigned short sBh[128 * 32];
    __shared__ unsigned short sAl[128 * 32];
    __shared__ unsigned short sBl[128 * 32];

    const int bid = blockIdx.x;
    const int cpx = gridDim.x >> 3;
    const int sw  = (bid & 7) * cpx + (bid >> 3);
    const int mb  = sw / nbx, nb = sw % nbx;
    const int m0 = mb * 128, n0 = nb * 128;

    const int t = threadIdx.x;
    const int l = t & 63, w = t >> 6;
    const int rm = (w >> 1) * 64;
    const int cn = (w & 1) * 64;
    const int lr = l & 15;
    const int kg = (l >> 4) * 16;

    const int r0 = 2 * w, r1 = 2 * w + 1;
    const int rowS0 = 16 * r0 + (l >> 2);
    const int rowS1 = 16 * r1 + (l >> 2);
    const int h0 = (l & 3) ^ ((rowS0 >> 1) & 3);
    const int h1 = (l & 3) ^ ((rowS1 >> 1) & 3);

    const unsigned short* gAh0 = Ah + (long)(m0 + rowS0) * K + 8 * h0;
    const unsigned short* gAh1 = Ah + (long)(m0 + rowS1) * K + 8 * h1;
    const unsigned short* gAl0 = Al + (long)(m0 + rowS0) * K + 8 * h0;
    const unsigned short* gAl1 = Al + (long)(m0 + rowS1) * K + 8 * h1;
    const unsigned short* gBh0 = Bh + (long)(n0 + rowS0) * K + 8 * h0;
    const unsigned short* gBh1 = Bh + (long)(n0 + rowS1) * K + 8 * h1;
    const unsigned short* gBl0 = Bl + (long)(n0 + rowS0) * K + 8 * h0;
    const unsigned short* gBl1 = Bl + (long)(n0 + rowS1) * K + 8 * h1;

    unsigned short* dA0 = &sAh[r0 * 512];
    unsigned short* dA1 = &sAh[r1 * 512];
    unsigned short* dAl0 = &sAl[r0 * 512];
    unsigned short* dAl1 = &sAl[r1 * 512];
    unsigned short* dB0 = &sBh[r0 * 512];
    unsigned short* dB1 = &sBh[r1 * 512];
    unsigned short* dBl0 = &sBl[r0 * 512];
    unsigned short* dBl1 = &sBl[r1 * 512];

    f32x4 acc[4][4];
    #pragma unroll
    for (int i = 0; i < 4; ++i)
        #pragma unroll
        for (int j = 0; j < 4; ++j)
            acc[i][j] = (f32x4){0.f, 0.f, 0.f, 0.f};

    const int nk = K >> 5;
    for (int it = 0; it < nk; ++it) {
        gl16(gAh0, dA0);  gl16(gAh1, dA1);
        gl16(gBh0, dB0);  gl16(gBh1, dB1);
        gl16(gAl0, dAl0); gl16(gAl1, dAl1);
        gl16(gBl0, dBl0); gl16(gBl1, dBl1);
        gAh0 += 32; gAh1 += 32; gAl0 += 32; gAl1 += 32;
        gBh0 += 32; gBh1 += 32; gBl0 += 32; gBl1 += 32;
        __syncthreads();

        s16x8 ah[4], bh[4];
        #pragma unroll
        for (int mi = 0; mi < 4; ++mi)
            ah[mi] = *(const s16x8*)((const char*)sAh + swz(rm + mi * 16 + lr, kg));
        #pragma unroll
        for (int nj = 0; nj < 4; ++nj)
            bh[nj] = *(const s16x8*)((const char*)sBh + swz(cn + nj * 16 + lr, kg));
        #pragma unroll
        for (int mi = 0; mi < 4; ++mi)
            #pragma unroll
            for (int nj = 0; nj < 4; ++nj)
                acc[mi][nj] = __builtin_amdgcn_mfma_f32_16x16x32_bf16(
                    ah[mi], bh[nj], acc[mi][nj], 0, 0, 0);
        s16x8 al[4], bl[4];
        #pragma unroll
        for (int mi = 0; mi < 4; ++mi)
            al[mi] = *(const s16x8*)((const char*)sAl + swz(rm + mi * 16 + lr, kg));
        #pragma unroll
        for (int mi = 0; mi < 4; ++mi)
            #pragma unroll
            for (int nj = 0; nj < 4; ++nj)
                acc[mi][nj] = __builtin_amdgcn_mfma_f32_16x16x32_bf16(
                    al[mi], bh[nj], acc[mi][nj], 0, 0, 0);
        #pragma unroll
        for (int nj = 0; nj < 4; ++nj)
            bl[nj] = *(const s16x8*)((const char*)sBl + swz(cn + nj * 16 + lr, kg));
        #pragma unroll
        for (int mi = 0; mi < 4; ++mi)
            #pragma unroll
            for (int nj = 0; nj < 4; ++nj)
                acc[mi][nj] = __builtin_amdgcn_mfma_f32_16x16x32_bf16(
                    ah[mi], bl[nj], acc[mi][nj], 0, 0, 0);
        __syncthreads();
    }

    #pragma unroll
    for (int mi = 0; mi < 4; ++mi) {
        #pragma unroll
        for (int nj = 0; nj < 4; ++nj) {
            const int row = m0 + rm + mi * 16 + (l >> 4) * 4;
            const int col = n0 + cn + nj * 16 + lr;
            const float badd = bias[col];
            #pragma unroll
            for (int r = 0; r < 4; ++r)
                C[(long)(row + r) * N + col] = acc[mi][nj][r] + badd;
        }
    }
}

__global__ __launch_bounds__(256, 1) void out_gemm(
    const float* __restrict__ A32, const unsigned short* __restrict__ B16,
    float* __restrict__ C, int M, int N, int K,
    long strideA, long strideB, long strideC)
{
    __shared__ unsigned short sA[128 * 32];
    __shared__ unsigned short sB[128 * 32];

    const int bz = blockIdx.z;
    const float* Ab = A32 + (long)bz * strideA;
    const unsigned short* Bb = B16 + (long)bz * strideB;
    float* Cb = C + (long)bz * strideC;
    const int m0 = blockIdx.x * 128;
    const int n0 = blockIdx.y * 128;

    const int t = threadIdx.x;
    const int l = t & 63, w = t >> 6;
    const int rm = (w >> 1) * 64;
    const int cn = (w & 1) * 64;
    const int lr = l & 15;
    const int kg = (l >> 4) * 16;

    const int r0 = 2 * w, r1 = 2 * w + 1;
    const int rowS0 = 16 * r0 + (l >> 2);
    const int rowS1 = 16 * r1 + (l >> 2);
    const int h0 = (l & 3) ^ ((rowS0 >> 1) & 3);
    const int h1 = (l & 3) ^ ((rowS1 >> 1) & 3);
    const unsigned short* gB0 = Bb + (long)(n0 + rowS0) * K + 8 * h0;
    const unsigned short* gB1 = Bb + (long)(n0 + rowS1) * K + 8 * h1;
    unsigned short* dB0 = &sB[r0 * 512];
    unsigned short* dB1 = &sB[r1 * 512];

    const int srow = t >> 1;
    const int skh  = (t & 1) * 16;
    const float* gA = &Ab[(long)(m0 + srow) * K + skh];

    f32x4 acc[4][4];
    #pragma unroll
    for (int i = 0; i < 4; ++i)
        #pragma unroll
        for (int j = 0; j < 4; ++j)
            acc[i][j] = (f32x4){0.f, 0.f, 0.f, 0.f};

    const int nk = K >> 5;
    for (int it = 0; it < nk; ++it) {
        gl16(gB0, dB0); gl16(gB1, dB1);
        gB0 += 32; gB1 += 32;
        {
            float f[16];
            #pragma unroll
            for (int q = 0; q < 4; ++q) {
                const float4 v = *(const float4*)(gA + 4 * q);
                f[4*q+0] = v.x; f[4*q+1] = v.y; f[4*q+2] = v.z; f[4*q+3] = v.w;
            }
            gA += 32;
            s16x8 v0, v1;
            #pragma unroll
            for (int q = 0; q < 8; ++q) {
                v0[q] = (short)f2bf(f[q]);
                v1[q] = (short)f2bf(f[8 + q]);
            }
            *(s16x8*)((char*)sA + swz(srow, skh * 2))      = v0;
            *(s16x8*)((char*)sA + swz(srow, skh * 2 + 16)) = v1;
        }
        __syncthreads();

        s16x8 ah[4], bh[4];
        #pragma unroll
        for (int mi = 0; mi < 4; ++mi)
            ah[mi] = *(const s16x8*)((const char*)sA + swz(rm + mi * 16 + lr, kg));
        #pragma unroll
        for (int nj = 0; nj < 4; ++nj)
            bh[nj] = *(const s16x8*)((const char*)sB + swz(cn + nj * 16 + lr, kg));
        #pragma unroll
        for (int mi = 0; mi < 4; ++mi)
            #pragma unroll
            for (int nj = 0; nj < 4; ++nj)
                acc[mi][nj] = __builtin_amdgcn_mfma_f32_16x16x32_bf16(
                    ah[mi], bh[nj], acc[mi][nj], 0, 0, 0);
        __syncthreads();
    }

    #pragma unroll
    for (int mi = 0; mi < 4; ++mi) {
        #pragma unroll
        for (int nj = 0; nj < 4; ++nj) {
            const int row = m0 + rm + mi * 16 + (l >> 4) * 4;
            const int col = n0 + cn + nj * 16 + lr;
            #pragma unroll
            for (int r = 0; r < 4; ++r)
                Cb[(long)(row + r) * N + col] = acc[mi][nj][r];
        }
    }
}

// ============================================================================
// small helper kernels
// ============================================================================
// MODE: 0 = fp32 out, 1 = bf16 out, 2 = fp16 out
template<int MODE>
__global__ __launch_bounds__(256) void transpose64(
    const float* __restrict__ in, void* __restrict__ outv,
    int R, int Cc, long sIn, long sOut)
{
    __shared__ float tl[64][65];
    const int z = blockIdx.z;
    const float* ib = in + (long)z * sIn;
    const int r0 = blockIdx.x * 64, c0 = blockIdx.y * 64;
    const int t = threadIdx.x;
    const int lrr = t >> 4, lc = (t & 15) * 4;
    #pragma unroll
    for (int p = 0; p < 4; ++p) {
        const float4 v = *(const float4*)&ib[(long)(r0 + lrr + 16 * p) * Cc + c0 + lc];
        tl[lrr + 16 * p][lc + 0] = v.x; tl[lrr + 16 * p][lc + 1] = v.y;
        tl[lrr + 16 * p][lc + 2] = v.z; tl[lrr + 16 * p][lc + 3] = v.w;
    }
    __syncthreads();
    #pragma unroll
    for (int p = 0; p < 4; ++p) {
        const int orow = c0 + lrr + 16 * p;
        const int ocol = r0 + lc;
        const float a = tl[lc + 0][lrr + 16 * p];
        const float b = tl[lc + 1][lrr + 16 * p];
        const float c = tl[lc + 2][lrr + 16 * p];
        const float d = tl[lc + 3][lrr + 16 * p];
        if (MODE == 1) {
            ushort4 u = { f2bf(a), f2bf(b), f2bf(c), f2bf(d) };
            *(ushort4*)((unsigned short*)outv + (long)z * sOut + (long)orow * R + ocol) = u;
        } else if (MODE == 2) {
            ushort4 u = { f2h(a), f2h(b), f2h(c), f2h(d) };
            *(ushort4*)((unsigned short*)outv + (long)z * sOut + (long)orow * R + ocol) = u;
        } else {
            float4 u = { a, b, c, d };
            *(float4*)((float*)outv + (long)z * sOut + (long)orow * R + ocol) = u;
        }
    }
}

// fp32 -> bf16 hi/lo (mid path)
__global__ __launch_bounds__(256) void convert_hilo(
    const float* __restrict__ src, unsigned short* __restrict__ hi,
    unsigned short* __restrict__ lo, long n8)
{
    for (long i = (long)blockIdx.x * blockDim.x + threadIdx.x; i < n8;
         i += (long)gridDim.x * blockDim.x) {
        const float4 a = *(const float4*)&src[i * 8];
        const float4 b = *(const float4*)&src[i * 8 + 4];
        const float f[8] = { a.x, a.y, a.z, a.w, b.x, b.y, b.z, b.w };
        s16x8 h, lv;
        #pragma unroll
        for (int q = 0; q < 8; ++q) {
            const unsigned short hh = f2bf(f[q]);
            h[q]  = (short)hh;
            lv[q] = (short)f2bf(f[q] - bf2f(hh));
        }
        *(s16x8*)&hi[i * 8] = h;
        *(s16x8*)&lo[i * 8] = lv;
    }
}

// fp32 [rows][Kd] -> fp16 interleaved [rows][2*Kd]: hi at col, lo at Kd+col.
__global__ __launch_bounds__(256) void convert_q_ilv(
    const float* __restrict__ src, unsigned short* __restrict__ dst,
    int kd8, long n8)   // kd8 = Kd/8
{
    const int Kd = kd8 * 8;
    for (long i = (long)blockIdx.x * blockDim.x + threadIdx.x; i < n8;
         i += (long)gridDim.x * blockDim.x) {
        const long row = i / kd8;
        const int  col = (int)(i - row * kd8) * 8;
        const float4 a = *(const float4*)&src[i * 8];
        const float4 b = *(const float4*)&src[i * 8 + 4];
        const float f[8] = { a.x, a.y, a.z, a.w, b.x, b.y, b.z, b.w };
        s16x8 h, lv;
        #pragma unroll
        for (int q = 0; q < 8; ++q) {
            const unsigned short hh = f2h(f[q]);
            h[q]  = (short)hh;
            lv[q] = (short)f2h(f[q] - h2f(hh));
        }
        unsigned short* dr = dst + row * (long)(2 * Kd);
        *(s16x8*)&dr[col]      = h;
        *(s16x8*)&dr[Kd + col] = lv;
    }
}

// fp32 [rows][Kd] -> fp16 duplicated [rows][2*Kd]: hi at col AND Kd+col.
__global__ __launch_bounds__(256) void convert_kw_dup(
    const float* __restrict__ src, unsigned short* __restrict__ dst,
    int kd8, long n8)
{
    const int Kd = kd8 * 8;
    for (long i = (long)blockIdx.x * blockDim.x + threadIdx.x; i < n8;
         i += (long)gridDim.x * blockDim.x) {
        const long row = i / kd8;
        const int  col = (int)(i - row * kd8) * 8;
        const float4 a = *(const float4*)&src[i * 8];
        const float4 b = *(const float4*)&src[i * 8 + 4];
        const float f[8] = { a.x, a.y, a.z, a.w, b.x, b.y, b.z, b.w };
        s16x8 h;
        #pragma unroll
        for (int q = 0; q < 8; ++q) h[q] = (short)f2h(f[q]);
        unsigned short* dr = dst + row * (long)(2 * Kd);
        *(s16x8*)&dr[col]      = h;
        *(s16x8*)&dr[Kd + col] = h;
    }
}

__global__ __launch_bounds__(256) void bk_dot(
    const float* __restrict__ key, const float* __restrict__ b,
    float* __restrict__ bk, int D)
{
    const int row = blockIdx.x * 4 + (threadIdx.x >> 6);
    const int l = threadIdx.x & 63;
    const float* kr = key + (long)row * D;
    float s = 0.f;
    for (int e = l; e < D; e += 64) s += kr[e] * b[e];
    #pragma unroll
    for (int off = 32; off > 0; off >>= 1) s += __shfl_xor(s, off);
    if (l == 0) bk[row] = s;
}

// Softmax from fp16 logits; writes fp32 attn + normalized fp16 IN-PLACE over
// the logit slot (exact 16B-per-thread alias, read-before-write). cols = 2048.
__global__ __launch_bounds__(256) void softmax_h16(
    unsigned short* __restrict__ L16, float* __restrict__ Afp, int cols)
{
    const long row = blockIdx.x;
    unsigned short* pl = L16 + row * (long)cols;
    float* pf = Afp + row * (long)cols;
    const int t = threadIdx.x;
    const int wid = t >> 6;
    const int base = t * 8;

    const s16x8 hv = *(const s16x8*)&pl[base];
    float vals[8];
    #pragma unroll
    for (int i = 0; i < 8; ++i) vals[i] = h2f((unsigned short)hv[i]);
    float m = -INFINITY;
    #pragma unroll
    for (int i = 0; i < 8; ++i) m = fmaxf(m, vals[i]);
    #pragma unroll
    for (int off = 32; off > 0; off >>= 1)
        m = fmaxf(m, __shfl_xor(m, off));
    __shared__ float smax[4], ssum[4];
    if ((t & 63) == 0) smax[wid] = m;
    __syncthreads();
    m = fmaxf(fmaxf(smax[0], smax[1]), fmaxf(smax[2], smax[3]));

    float s = 0.f;
    #pragma unroll
    for (int i = 0; i < 8; ++i) {
        vals[i] = __expf(vals[i] - m);
        s += vals[i];
    }
    #pragma unroll
    for (int off = 32; off > 0; off >>= 1)
        s += __shfl_xor(s, off);
    if ((t & 63) == 0) ssum[wid] = s;
    __syncthreads();
    s = (ssum[0] + ssum[1]) + (ssum[2] + ssum[3]);
    const float inv = 1.0f / s;

    float4 o0, o1;
    o0.x = vals[0]*inv; o0.y = vals[1]*inv; o0.z = vals[2]*inv; o0.w = vals[3]*inv;
    o1.x = vals[4]*inv; o1.y = vals[5]*inv; o1.z = vals[6]*inv; o1.w = vals[7]*inv;
    *(float4*)&pf[base]     = o0;
    *(float4*)&pf[base + 4] = o1;
    s16x8 h;
    h[0]=(short)f2h(o0.x); h[1]=(short)f2h(o0.y); h[2]=(short)f2h(o0.z); h[3]=(short)f2h(o0.w);
    h[4]=(short)f2h(o1.x); h[5]=(short)f2h(o1.y); h[6]=(short)f2h(o1.z); h[7]=(short)f2h(o1.w);
    *(s16x8*)&pl[base] = h;
}

// In-place row softmax + fp16 copy (fp32-logit path); cols = 2048.
__global__ __launch_bounds__(256) void softmax_f16(
    float* __restrict__ S, unsigned short* __restrict__ S16, int cols)
{
    const long row = blockIdx.x;
    float* p = S + row * (long)cols;
    unsigned short* p16 = S16 + row * (long)cols;
    const int t = threadIdx.x;
    const int wid = t >> 6;
    const int base = t * 8;

    const float4 a = *(const float4*)&p[base];
    const float4 b = *(const float4*)&p[base + 4];
    float vals[8] = { a.x, a.y, a.z, a.w, b.x, b.y, b.z, b.w };
    float m = -INFINITY;
    #pragma unroll
    for (int i = 0; i < 8; ++i) m = fmaxf(m, vals[i]);
    #pragma unroll
    for (int off = 32; off > 0; off >>= 1)
        m = fmaxf(m, __shfl_xor(m, off));
    __shared__ float smax[4], ssum[4];
    if ((t & 63) == 0) smax[wid] = m;
    __syncthreads();
    m = fmaxf(fmaxf(smax[0], smax[1]), fmaxf(smax[2], smax[3]));

    float s = 0.f;
    #pragma unroll
    for (int i = 0; i < 8; ++i) {
        vals[i] = __expf(vals[i] - m);
        s += vals[i];
    }
    #pragma unroll
    for (int off = 32; off > 0; off >>= 1)
        s += __shfl_xor(s, off);
    if ((t & 63) == 0) ssum[wid] = s;
    __syncthreads();
    s = (ssum[0] + ssum[1]) + (ssum[2] + ssum[3]);
    const float inv = 1.0f / s;

    float4 o0, o1;
    o0.x = vals[0]*inv; o0.y = vals[1]*inv; o0.z = vals[2]*inv; o0.w = vals[3]*inv;
    o1.x = vals[4]*inv; o1.y = vals[5]*inv; o1.z = vals[6]*inv; o1.w = vals[7]*inv;
    *(float4*)&p[base]     = o0;
    *(float4*)&p[base + 4] = o1;
    s16x8 h;
    h[0]=(short)f2h(o0.x); h[1]=(short)f2h(o0.y); h[2]=(short)f2h(o0.z); h[3]=(short)f2h(o0.w);
    h[4]=(short)f2h(o1.x); h[5]=(short)f2h(o1.y); h[6]=(short)f2h(o1.z); h[7]=(short)f2h(o1.w);
    *(s16x8*)&p16[base] = h;
}

// plain softmax (mid/fallback paths)
__global__ __launch_bounds__(256) void softmax_rows(float* __restrict__ S, int cols)
{
    const long row = blockIdx.x;
    float* p = S + row * (long)cols;
    const int t = threadIdx.x;
    const int wid = t >> 6;

    float vals[8];
    float m = -INFINITY;
    #pragma unroll
    for (int i = 0; i < 8; ++i) {
        vals[i] = p[t + i * 256];
        m = fmaxf(m, vals[i]);
    }
    #pragma unroll
    for (int off = 32; off > 0; off >>= 1)
        m = fmaxf(m, __shfl_xor(m, off));
    __shared__ float smax[4], ssum[4];
    if ((t & 63) == 0) smax[wid] = m;
    __syncthreads();
    m = fmaxf(fmaxf(smax[0], smax[1]), fmaxf(smax[2], smax[3]));

    float s = 0.f;
    #pragma unroll
    for (int i = 0; i < 8; ++i) {
        vals[i] = __expf(vals[i] - m);
        s += vals[i];
    }
    #pragma unroll
    for (int off = 32; off > 0; off >>= 1)
        s += __shfl_xor(s, off);
    if ((t & 63) == 0) ssum[wid] = s;
    __syncthreads();
    s = (ssum[0] + ssum[1]) + (ssum[2] + ssum[3]);
    const float inv = 1.0f / s;
    #pragma unroll
    for (int i = 0; i < 8; ++i)
        p[t + i * 256] = vals[i] * inv;
}

// ============================================================================
extern "C" void kernel_launch(void* const* d_in, const int* in_sizes, int n_in,
                              void* d_out, int out_size, void* d_ws, size_t ws_size,
                              hipStream_t stream)
{
    const float* query = (const float*)d_in[0];  // [B, Nq, D]
    const float* key   = (const float*)d_in[1];  // [Nk, D]
    const float* x     = (const float*)d_in[2];  // [B, Nk, D]
    const float* W     = (const float*)d_in[3];  // [D, D]
    const float* bias  = (const float*)d_in[4];  // [D]

    const int D  = in_sizes[4];                  // 768
    const int Nk = in_sizes[1] / D;              // 2048
    const int B  = in_sizes[2] / (Nk * D);       // 8
    const int Nq = in_sizes[0] / (B * D);        // 2048

    float* out  = (float*)d_out;                 // [B, Nq, D]
    float* attn = out + (long)B * Nq * D;        // [B, Nq, Nk]

    const long nQ  = (long)B * Nq * D;           // 12,582,912
    const long nKW = (long)Nk * D;               // 1,572,864
    const long nX  = (long)B * Nk * D;           // 12,582,912
    const int  M   = B * Nq;                     // 16384
    const int  K2  = 2 * D;                      // 1536

    const size_t xTb    = (size_t)nX * 2;                // 25.2 MB
    const size_t kwDupB = (size_t)Nk * K2 * 2;           // 6.3 MB
    const size_t bkB    = (size_t)Nk * 4;                // 8 KB
    const size_t atb1   = (size_t)Nq * Nk * 2;           // 8.39 MB per batch
    const size_t fixedB = xTb + kwDupB + bkB;            // ~31.5 MB
    const size_t qLob   = (size_t)nQ * 2;
    const size_t wsMid  = xTb + qLob;                    // 50.3 MB (mid path)
    const size_t wsF16  = fixedB + 4 * atb1;             // ~65.1 MB (fp16-logit path)

    int g = 0;
    if (ws_size >= fixedB + 2 * atb1) {
        g = (int)((ws_size - fixedB) / atb1);
        if (g > B) g = B;
    }

    if (ws_size >= wsF16 && B == 8) {
        // ----- fastest path: fp16 logits, 4-batch slot, 2 full-fill score launches -----
        unsigned short* qIlv  = (unsigned short*)out;   // out region scratch
        unsigned short* xT    = (unsigned short*)d_ws;
        unsigned short* kwDup = (unsigned short*)((char*)d_ws + xTb);
        float*          bk    = (float*)((char*)d_ws + xTb + kwDupB);
        unsigned short* slot  = (unsigned short*)((char*)d_ws + fixedB);  // 4 batches
        float* Wt  = attn;                              // attn region scratch
        float* KWf = attn + 1048576;

        dim3 gtw(D / 64, D / 64, 1);
        transpose64<0><<<gtw, 256, 0, stream>>>(W, Wt, D, D, 0L, 0L);
        dim3 gkw(D / 128, Nk / 128, 1);
        mfma_gemm<3, false, false><<<gkw, 256, 0, stream>>>(
            key, Wt, nullptr, KWf, Nk, D, D, 0L, 0L, 0L);
        convert_kw_dup<<<768, 256, 0, stream>>>(KWf, kwDup, D / 8, nKW / 8);
        bk_dot<<<Nk / 4, 256, 0, stream>>>(key, bias, bk, D);
        convert_q_ilv<<<2048, 256, 0, stream>>>(query, qIlv, D / 8, nQ / 8);
        dim3 gtx(Nk / 64, D / 64, B);
        transpose64<2><<<gtx, 256, 0, stream>>>(
            x, xT, Nk, D, (long)Nk * D, (long)D * Nk);

        const int nbx = Nk / 256;                        // 8
        for (int grp = 0; grp < 2; ++grp) {
            const int b0 = grp * 4;
            const int nwg = (4 * Nq / 256) * nbx;        // 256 = full fill
            score_8ph<1><<<nwg, 512, 0, stream>>>(
                qIlv + (long)b0 * Nq * K2, kwDup, bk, slot, 4 * Nq, Nk, K2, nbx);
            softmax_h16<<<4 * Nq, 256, 0, stream>>>(
                slot, attn + (long)b0 * Nq * Nk, Nk);
            dim3 go(Nq / 128, D / 128, 4);
            pv_2ph<<<go, 256, 0, stream>>>(
                slot, xT + (long)b0 * D * Nk, out + (long)b0 * Nq * D,
                Nq, D, Nk, (long)Nq * Nk, (long)D * Nk, (long)Nq * D);
        }
    } else if (g >= 2) {
        // ----- fp32-logit fast path -----
        unsigned short* qIlv  = (unsigned short*)out;
        unsigned short* xT     = (unsigned short*)d_ws;
        unsigned short* kwDup  = (unsigned short*)((char*)d_ws + xTb);
        float*          bk     = (float*)((char*)d_ws + xTb + kwDupB);
        unsigned short* attn16 = (unsigned short*)((char*)d_ws + fixedB);
        float* Wt  = attn;
        float* KWf = attn + 1048576;

        dim3 gtw(D / 64, D / 64, 1);
        transpose64<0><<<gtw, 256, 0, stream>>>(W, Wt, D, D, 0L, 0L);
        dim3 gkw(D / 128, Nk / 128, 1);
        mfma_gemm<3, false, false><<<gkw, 256, 0, stream>>>(
            key, Wt, nullptr, KWf, Nk, D, D, 0L, 0L, 0L);
        convert_kw_dup<<<768, 256, 0, stream>>>(KWf, kwDup, D / 8, nKW / 8);
        bk_dot<<<Nk / 4, 256, 0, stream>>>(key, bias, bk, D);
        convert_q_ilv<<<2048, 256, 0, stream>>>(query, qIlv, D / 8, nQ / 8);
        dim3 gtx(Nk / 64, D / 64, B);
        transpose64<2><<<gtx, 256, 0, stream>>>(
            x, xT, Nk, D, (long)Nk * D, (long)D * Nk);

        const int nbx = Nk / 256;                        // 8
        const int nwg = (M / 256) * nbx;                 // 512
        score_8ph<0><<<nwg, 512, 0, stream>>>(
            qIlv, kwDup, bk, attn, M, Nk, K2, nbx);

        for (int b0 = 0; b0 < B; b0 += g) {
            const int gb = (b0 + g <= B) ? g : (B - b0);
            softmax_f16<<<gb * Nq, 256, 0, stream>>>(
                attn + (long)b0 * Nq * Nk, attn16, Nk);
            dim3 go(Nq / 128, D / 128, gb);
            pv_2ph<<<go, 256, 0, stream>>>(
                attn16, xT + (long)b0 * D * Nk, out + (long)b0 * Nq * D,
                Nq, D, Nk, (long)Nq * Nk, (long)D * Nk, (long)Nq * D);
        }
    } else if (ws_size >= wsMid) {
        // ---------------- mid path (bf16 3-pass) ----------------
        unsigned short* q_hi  = (unsigned short*)out;
        unsigned short* KW_hi = q_hi + nQ;
        unsigned short* KW_lo = KW_hi + nKW;
        float*          bk    = (float*)(KW_lo + nKW);
        unsigned short* q_lo  = (unsigned short*)d_ws;
        unsigned short* xT    = q_lo + nQ;
        float* Wt  = attn;
        float* KWf = attn + 1048576;

        dim3 gtw(D / 64, D / 64, 1);
        transpose64<0><<<gtw, 256, 0, stream>>>(W, Wt, D, D, 0L, 0L);
        dim3 gkw(D / 128, Nk / 128, 1);
        mfma_gemm<3, false, false><<<gkw, 256, 0, stream>>>(
            key, Wt, nullptr, KWf, Nk, D, D, 0L, 0L, 0L);
        convert_hilo<<<768, 256, 0, stream>>>(KWf, KW_hi, KW_lo, nKW / 8);
        bk_dot<<<Nk / 4, 256, 0, stream>>>(key, bias, bk, D);
        convert_hilo<<<2048, 256, 0, stream>>>(query, q_hi, q_lo, nQ / 8);
        dim3 gtx(Nk / 64, D / 64, B);
        transpose64<1><<<gtx, 256, 0, stream>>>(
            x, xT, Nk, D, (long)Nk * D, (long)D * Nk);
        const int nbx = Nk / 128;
        const int nwg = (B * Nq / 128) * nbx;
        score_gemm<<<nwg, 256, 0, stream>>>(
            q_hi, q_lo, KW_hi, KW_lo, bk, attn, B * Nq, Nk, D, nbx);
        softmax_rows<<<B * Nq, 256, 0, stream>>>(attn, Nk);
        dim3 go(Nq / 128, D / 128, B);
        out_gemm<<<go, 256, 0, stream>>>(
            attn, xT, out, Nq, D, Nk, (long)Nq * Nk, (long)D * Nk, (long)Nq * D);
    } else {
        // ---------------- round-2 fallback ----------------
        float* qp = out;
        dim3 g1(D / 128, (B * Nq) / 128, 1);
        mfma_gemm<3, false, true><<<g1, 256, 0, stream>>>(
            query, W, bias, qp, B * Nq, D, D, 0L, 0L, 0L);
        dim3 g2(Nk / 128, Nq / 128, B);
        mfma_gemm<3, false, false><<<g2, 256, 0, stream>>>(
            qp, key, nullptr, attn, Nq, Nk, D, (long)Nq * D, 0L, (long)Nq * Nk);
        softmax_rows<<<B * Nq, 256, 0, stream>>>(attn, Nk);
        dim3 g4(D / 128, Nq / 128, B);
        mfma_gemm<1, true, false><<<g4, 256, 0, stream>>>(
            attn, x, nullptr, out, Nq, D, Nk, (long)Nq * Nk, (long)Nk * D, (long)Nq * D);
    }
}